// Round 1
// baseline (566.231 us; speedup 1.0000x reference)
//
#include <hip/hip_runtime.h>
#include <math.h>

#define NNODES 50000
#define MINC   200000
#define NEDGE  20000
#define NIND   8

// ===================== QI = I @ wq + bq  (8x64) =====================
__global__ void qi_kernel(const float* __restrict__ I, const float* __restrict__ wq,
                          const float* __restrict__ bq, float* __restrict__ QI) {
    int tid = threadIdx.x;            // 512 threads, 1 block
    int i = tid >> 6, c = tid & 63;
    float acc = bq[c];
    for (int k = 0; k < 64; ++k) acc += I[i * 64 + k] * wq[k * 64 + c];
    QI[i * 64 + c] = acc;
}

// ============ C1 = A@W1+b1 (and optionally C2 = A@W2+b2) ============
template<bool TWO>
__global__ void linear_kernel(const float* __restrict__ A, int N,
                              const float* __restrict__ W1, const float* __restrict__ b1,
                              float* __restrict__ C1,
                              const float* __restrict__ W2, const float* __restrict__ b2,
                              float* __restrict__ C2) {
    __shared__ float Ws1[64 * 64];
    __shared__ float Ws2[TWO ? 64 * 64 : 1];
    __shared__ float As[32][65];
    int tid = threadIdx.x;  // 256
    for (int k = tid; k < 4096; k += 256) {
        Ws1[k] = W1[k];
        if (TWO) Ws2[k] = W2[k];
    }
    int row0 = blockIdx.x * 32;
    for (int k = tid; k < 2048; k += 256) {
        int r = k >> 6, c = k & 63;
        int gr = row0 + r;
        As[r][c] = (gr < N) ? A[gr * 64 + c] : 0.f;
    }
    __syncthreads();
    int c = tid & 63, r0 = tid >> 6;         // wave-uniform r0
    float acc1[8] = {0, 0, 0, 0, 0, 0, 0, 0};
    float acc2[8] = {0, 0, 0, 0, 0, 0, 0, 0};
    for (int k = 0; k < 64; ++k) {
        float w1 = Ws1[k * 64 + c];
        float w2 = TWO ? Ws2[k * 64 + c] : 0.f;
        #pragma unroll
        for (int rr = 0; rr < 8; ++rr) {
            float a = As[r0 + rr * 4][k];    // LDS broadcast within wave
            acc1[rr] += a * w1;
            if (TWO) acc2[rr] += a * w2;
        }
    }
    float bb1 = b1[c];
    float bb2 = TWO ? b2[c] : 0.f;
    #pragma unroll
    for (int rr = 0; rr < 8; ++rr) {
        int gr = row0 + r0 + rr * 4;
        if (gr < N) {
            C1[gr * 64 + c] = acc1[rr] + bb1;
            if (TWO) C2[gr * 64 + c] = acc2[rr] + bb2;
        }
    }
}

// =================== O = A + relu(A@W + b) ===================
__global__ void linear_relu_res_kernel(const float* __restrict__ A, int N,
                                       const float* __restrict__ W, const float* __restrict__ b,
                                       float* __restrict__ O) {
    __shared__ float Ws[64 * 64];
    __shared__ float As[32][65];
    int tid = threadIdx.x;  // 256
    for (int k = tid; k < 4096; k += 256) Ws[k] = W[k];
    int row0 = blockIdx.x * 32;
    for (int k = tid; k < 2048; k += 256) {
        int r = k >> 6, cc = k & 63;
        int gr = row0 + r;
        As[r][cc] = (gr < N) ? A[gr * 64 + cc] : 0.f;
    }
    __syncthreads();
    int c = tid & 63, r0 = tid >> 6;
    float acc[8] = {0, 0, 0, 0, 0, 0, 0, 0};
    for (int k = 0; k < 64; ++k) {
        float w = Ws[k * 64 + c];
        #pragma unroll
        for (int rr = 0; rr < 8; ++rr) acc[rr] += As[r0 + rr * 4][k] * w;
    }
    float bb = b[c];
    #pragma unroll
    for (int rr = 0; rr < 8; ++rr) {
        int r = r0 + rr * 4, gr = row0 + r;
        if (gr < N) {
            float x = As[r][c];
            float t = acc[rr] + bb;
            O[gr * 64 + c] = x + (t > 0.f ? t : 0.f);
        }
    }
}

// ===================== CSR build =====================
__global__ void hist_kernel(const int* __restrict__ edge, int* __restrict__ cnt) {
    int m = blockIdx.x * 256 + threadIdx.x;
    if (m < MINC) atomicAdd(&cnt[edge[m]], 1);
}

__global__ void scan_kernel(const int* __restrict__ cnt, int* __restrict__ rowstart,
                            int* __restrict__ cursor) {
    __shared__ int partial[1024];
    int tid = threadIdx.x;                       // 1024
    const int CH = (NEDGE + 1023) / 1024;        // 20
    int s = 0;
    for (int k = 0; k < CH; ++k) {
        int idx = tid * CH + k;
        if (idx < NEDGE) s += cnt[idx];
    }
    partial[tid] = s;
    __syncthreads();
    for (int off = 1; off < 1024; off <<= 1) {
        int v = 0;
        if (tid >= off) v = partial[tid - off];
        __syncthreads();
        if (tid >= off) partial[tid] += v;
        __syncthreads();
    }
    int base = (tid > 0) ? partial[tid - 1] : 0;
    for (int k = 0; k < CH; ++k) {
        int idx = tid * CH + k;
        if (idx < NEDGE) {
            rowstart[idx] = base;
            cursor[idx] = base;
            base += cnt[idx];
        }
    }
    if (tid == 1023) rowstart[NEDGE] = base;     // = MINC
}

__global__ void scatter_kernel(const int* __restrict__ node, const int* __restrict__ edge,
                               int* __restrict__ cursor, int* __restrict__ csr_node) {
    int m = blockIdx.x * 256 + threadIdx.x;
    if (m < MINC) {
        int pos = atomicAdd(&cursor[edge[m]], 1);
        csr_node[pos] = node[m];
    }
}

// ===================== mab0 attention =====================
// grid = NEDGE blocks, 512 threads: wave i = inducing point, lane = h*16+d.
// Online softmax over the edge's incidences; writes head-permuted Opre0.
__global__ void attn0_kernel(const float* __restrict__ K0, const float* __restrict__ V0,
                             const float* __restrict__ QI,
                             const int* __restrict__ rowstart, const int* __restrict__ csr_node,
                             float* __restrict__ Opre0) {
    int e = blockIdx.x;
    int tid = threadIdx.x;        // 512
    int i = tid >> 6;             // 0..7
    int lane = tid & 63;          // h*16+d
    int h = lane >> 4, d = lane & 15;
    int start = rowstart[e], end = rowstart[e + 1];
    float qi = QI[i * 64 + lane];
    float m_run = -INFINITY, l_run = 0.f, acc = 0.f;
    for (int p = start; p < end; ++p) {
        int n = csr_node[p];
        float kv = K0[n * 64 + lane];
        float prod = qi * kv;
        prod += __shfl_xor(prod, 1);
        prod += __shfl_xor(prod, 2);
        prod += __shfl_xor(prod, 4);
        prod += __shfl_xor(prod, 8);
        float a = prod * 0.125f;              // / sqrt(64)
        float v = V0[n * 64 + lane];
        float m_new = fmaxf(m_run, a);
        float scale = __expf(m_run - m_new);  // 0 on first iter
        float w = __expf(a - m_new);
        l_run = l_run * scale + w;
        acc = acc * scale + w * v;
        m_run = m_new;
    }
    float out = qi + ((l_run > 0.f) ? acc / l_run : 0.f);
    Opre0[(e * NIND + i) * 64 + d * 4 + h] = out;   // head-permuted layout
}

// ===================== mab1 attention =====================
// 1 wave per incidence m; softmax over the 8 inducing rows per head.
__global__ void attn1_kernel(const float* __restrict__ Q1, const float* __restrict__ K1,
                             const float* __restrict__ V1,
                             const int* __restrict__ node, const int* __restrict__ edge,
                             float* __restrict__ Opre1) {
    int gid = blockIdx.x * 256 + threadIdx.x;
    int m = gid >> 6;
    if (m >= MINC) return;
    int lane = threadIdx.x & 63;
    int h = lane >> 4, d = lane & 15;
    int n = node[m];
    int e = edge[m];
    float q = Q1[n * 64 + lane];
    float a[8], v[8];
    #pragma unroll
    for (int i = 0; i < 8; ++i) {
        int row = e * NIND + i;
        float kv = K1[row * 64 + lane];
        float prod = q * kv;
        prod += __shfl_xor(prod, 1);
        prod += __shfl_xor(prod, 2);
        prod += __shfl_xor(prod, 4);
        prod += __shfl_xor(prod, 8);
        a[i] = prod * 0.125f;
        v[i] = V1[row * 64 + lane];
    }
    float mx = a[0];
    #pragma unroll
    for (int i = 1; i < 8; ++i) mx = fmaxf(mx, a[i]);
    float l = 0.f, acc = 0.f;
    #pragma unroll
    for (int i = 0; i < 8; ++i) {
        float w = __expf(a[i] - mx);
        l += w;
        acc += w * v[i];
    }
    float out = q + acc / l;
    Opre1[m * 64 + d * 4 + h] = out;   // head-permuted layout
}

// ===================== host launch =====================
extern "C" void kernel_launch(void* const* d_in, const int* in_sizes, int n_in,
                              void* d_out, int out_size, void* d_ws, size_t ws_size,
                              hipStream_t stream) {
    const float* X    = (const float*)d_in[0];
    const int*   hei  = (const int*)d_in[1];       // [2, M]: node row then edge row
    const float* I    = (const float*)d_in[2];
    const float* m0_wq = (const float*)d_in[3];
    const float* m0_bq = (const float*)d_in[4];
    const float* m0_wk = (const float*)d_in[5];
    const float* m0_bk = (const float*)d_in[6];
    const float* m0_wv = (const float*)d_in[7];
    const float* m0_bv = (const float*)d_in[8];
    const float* m0_wo = (const float*)d_in[9];
    const float* m0_bo = (const float*)d_in[10];
    const float* m1_wq = (const float*)d_in[11];
    const float* m1_bq = (const float*)d_in[12];
    const float* m1_wk = (const float*)d_in[13];
    const float* m1_bk = (const float*)d_in[14];
    const float* m1_wv = (const float*)d_in[15];
    const float* m1_bv = (const float*)d_in[16];
    const float* m1_wo = (const float*)d_in[17];
    const float* m1_bo = (const float*)d_in[18];

    const int* node = hei;           // [M]
    const int* edge = hei + MINC;    // [M]
    float* out = (float*)d_out;

    // -------- workspace layout (floats), lifetime-overlapped --------
    float* F = (float*)d_ws;
    float* K0    = F + 0;            // 3.2M   (phase A)
    float* V0    = F + 3200000;      // 3.2M   (phase A)
    float* Opre1 = F + 0;            // 12.8M  (phase B; aliases K0/V0 after attn0)
    float* Opre0 = F + 12800000;     // 10.24M (phase A)
    float* K1    = F + 12800000;     // 10.24M (phase B; aliases Opre0 after H built)
    float* H     = F + 23040000;     // 10.24M
    float* Q1    = F + 23040000;     // 3.2M   (aliases H after K1/V1 built)
    float* V1    = F + 33280000;     // 10.24M
    float* QI    = F + 43520000;     // 512
    int*   ib       = (int*)(F + 43520512);
    int*   rowstart = ib;                    // NE+1
    int*   cnt      = rowstart + (NEDGE + 1);
    int*   cursor   = cnt + NEDGE;
    int*   csr_node = cursor + NEDGE;        // M

    // ---------------- Phase A: mab0 ----------------
    qi_kernel<<<1, 512, 0, stream>>>(I, m0_wq, m0_bq, QI);
    linear_kernel<true><<<(NNODES + 31) / 32, 256, 0, stream>>>(
        X, NNODES, m0_wk, m0_bk, K0, m0_wv, m0_bv, V0);

    hipMemsetAsync(cnt, 0, NEDGE * sizeof(int), stream);
    hist_kernel<<<(MINC + 255) / 256, 256, 0, stream>>>(edge, cnt);
    scan_kernel<<<1, 1024, 0, stream>>>(cnt, rowstart, cursor);
    scatter_kernel<<<(MINC + 255) / 256, 256, 0, stream>>>(node, edge, cursor, csr_node);

    attn0_kernel<<<NEDGE, 512, 0, stream>>>(K0, V0, QI, rowstart, csr_node, Opre0);
    linear_relu_res_kernel<<<(NEDGE * NIND + 31) / 32, 256, 0, stream>>>(
        Opre0, NEDGE * NIND, m0_wo, m0_bo, H);

    // ---------------- Phase B: mab1 ----------------
    linear_kernel<true><<<(NEDGE * NIND + 31) / 32, 256, 0, stream>>>(
        H, NEDGE * NIND, m1_wk, m1_bk, K1, m1_wv, m1_bv, V1);
    linear_kernel<false><<<(NNODES + 31) / 32, 256, 0, stream>>>(
        X, NNODES, m1_wq, m1_bq, Q1, nullptr, nullptr, nullptr);

    attn1_kernel<<<(MINC * 64 + 255) / 256, 256, 0, stream>>>(
        Q1, K1, V1, node, edge, Opre1);
    linear_relu_res_kernel<<<(MINC + 31) / 32, 256, 0, stream>>>(
        Opre1, MINC, m1_wo, m1_bo, out);
}

// Round 2
// 520.893 us; speedup vs baseline: 1.0870x; 1.0870x over previous
//
#include <hip/hip_runtime.h>
#include <math.h>

#define NNODES 50000
#define MINC   200000
#define NEDGE  20000
#define NIND   8

// ---------- DPP 16-lane rotate-add reduction (pure VALU, no LDS) ----------
__device__ __forceinline__ float sum16(float x) {
    int v;
    v = __builtin_amdgcn_update_dpp(0, __float_as_int(x), 0x121, 0xf, 0xf, true); // row_ror:1
    x += __int_as_float(v);
    v = __builtin_amdgcn_update_dpp(0, __float_as_int(x), 0x122, 0xf, 0xf, true); // row_ror:2
    x += __int_as_float(v);
    v = __builtin_amdgcn_update_dpp(0, __float_as_int(x), 0x124, 0xf, 0xf, true); // row_ror:4
    x += __int_as_float(v);
    v = __builtin_amdgcn_update_dpp(0, __float_as_int(x), 0x128, 0xf, 0xf, true); // row_ror:8
    x += __int_as_float(v);
    return x;
}

// ===================== QI = I @ wq + bq  (8x64) =====================
__global__ void qi_kernel(const float* __restrict__ I, const float* __restrict__ wq,
                          const float* __restrict__ bq, float* __restrict__ QI) {
    int tid = threadIdx.x;            // 512 threads, 1 block
    int i = tid >> 6, c = tid & 63;
    float acc = bq[c];
    for (int k = 0; k < 64; ++k) acc += I[i * 64 + k] * wq[k * 64 + c];
    QI[i * 64 + c] = acc;
}

// ========= Wf[k, i*4+h] = 0.125 * sum_d wk[k, h*16+d] * QI[i, h*16+d] =========
__global__ void fuse_kernel(const float* __restrict__ QI, const float* __restrict__ wk,
                            const float* __restrict__ bk,
                            float* __restrict__ Wf, float* __restrict__ bf) {
    int tid = threadIdx.x; // 512
    for (int idx = tid; idx < 2048; idx += 512) {
        int k = idx >> 5, j = idx & 31;
        int i = j >> 2, h = j & 3;
        float s = 0.f;
        for (int d = 0; d < 16; ++d)
            s += wk[k * 64 + h * 16 + d] * QI[i * 64 + h * 16 + d];
        Wf[idx] = s * 0.125f;
    }
    if (tid < 32) {
        int i = tid >> 2, h = tid & 3;
        float s = 0.f;
        for (int d = 0; d < 16; ++d)
            s += bk[h * 16 + d] * QI[i * 64 + h * 16 + d];
        bf[tid] = s * 0.125f;
    }
}

// ====== V0 = X@Wv+bv (64 cols) and S0 = X@Wf+bf (32 cols), one X pass ======
__global__ void linear_dual_kernel(const float* __restrict__ A, int N,
                                   const float* __restrict__ Wv, const float* __restrict__ bv,
                                   float* __restrict__ V0,
                                   const float* __restrict__ Wf, const float* __restrict__ bf,
                                   float* __restrict__ S0) {
    __shared__ float Wvs[4096];
    __shared__ float Wfs[2048];
    __shared__ float As[32][65];
    int tid = threadIdx.x; // 256
    for (int k = tid; k < 4096; k += 256) Wvs[k] = Wv[k];
    for (int k = tid; k < 2048; k += 256) Wfs[k] = Wf[k];
    int row0 = blockIdx.x * 32;
    for (int k = tid; k < 2048; k += 256) {
        int r = k >> 6, c = k & 63;
        int gr = row0 + r;
        As[r][c] = (gr < N) ? A[gr * 64 + c] : 0.f;
    }
    __syncthreads();
    int c = tid & 63, c2 = c & 31, r0 = tid >> 6;
    float acc1[8] = {}, acc2[8] = {};
    for (int k = 0; k < 64; ++k) {
        float w1 = Wvs[k * 64 + c];
        float w2 = Wfs[k * 32 + c2];
        #pragma unroll
        for (int rr = 0; rr < 8; ++rr) {
            float a = As[r0 + rr * 4][k];
            acc1[rr] += a * w1;
            acc2[rr] += a * w2;
        }
    }
    float bb1 = bv[c];
    float bb2 = bf[c2];
    #pragma unroll
    for (int rr = 0; rr < 8; ++rr) {
        int gr = row0 + r0 + rr * 4;
        if (gr < N) {
            V0[gr * 64 + c] = acc1[rr] + bb1;
            if (c < 32) S0[gr * 32 + c] = acc2[rr] + bb2;
        }
    }
}

// =================== C = A@W + b (single output) ===================
__global__ void linear_kernel(const float* __restrict__ A, int N,
                              const float* __restrict__ W, const float* __restrict__ b,
                              float* __restrict__ C) {
    __shared__ float Ws[4096];
    __shared__ float As[32][65];
    int tid = threadIdx.x;  // 256
    for (int k = tid; k < 4096; k += 256) Ws[k] = W[k];
    int row0 = blockIdx.x * 32;
    for (int k = tid; k < 2048; k += 256) {
        int r = k >> 6, c = k & 63;
        int gr = row0 + r;
        As[r][c] = (gr < N) ? A[gr * 64 + c] : 0.f;
    }
    __syncthreads();
    int c = tid & 63, r0 = tid >> 6;
    float acc[8] = {};
    for (int k = 0; k < 64; ++k) {
        float w = Ws[k * 64 + c];
        #pragma unroll
        for (int rr = 0; rr < 8; ++rr) acc[rr] += As[r0 + rr * 4][k] * w;
    }
    float bb = b[c];
    #pragma unroll
    for (int rr = 0; rr < 8; ++rr) {
        int gr = row0 + r0 + rr * 4;
        if (gr < N) C[gr * 64 + c] = acc[rr] + bb;
    }
}

// =================== O = A + relu(A@W + b) ===================
__global__ void linear_relu_res_kernel(const float* __restrict__ A, int N,
                                       const float* __restrict__ W, const float* __restrict__ b,
                                       float* __restrict__ O) {
    __shared__ float Ws[4096];
    __shared__ float As[32][65];
    int tid = threadIdx.x;  // 256
    for (int k = tid; k < 4096; k += 256) Ws[k] = W[k];
    int row0 = blockIdx.x * 32;
    for (int k = tid; k < 2048; k += 256) {
        int r = k >> 6, cc = k & 63;
        int gr = row0 + r;
        As[r][cc] = (gr < N) ? A[gr * 64 + cc] : 0.f;
    }
    __syncthreads();
    int c = tid & 63, r0 = tid >> 6;
    float acc[8] = {};
    for (int k = 0; k < 64; ++k) {
        float w = Ws[k * 64 + c];
        #pragma unroll
        for (int rr = 0; rr < 8; ++rr) acc[rr] += As[r0 + rr * 4][k] * w;
    }
    float bb = b[c];
    #pragma unroll
    for (int rr = 0; rr < 8; ++rr) {
        int r = r0 + rr * 4, gr = row0 + r;
        if (gr < N) {
            float x = As[r][c];
            float t = acc[rr] + bb;
            O[gr * 64 + c] = x + (t > 0.f ? t : 0.f);
        }
    }
}

// === fused: H = Opre0 + relu(Opre0@wo+bo) (LDS only); K1 = H@wk+bk; V1 = H@wv+bv ===
__global__ void fused_hkv_kernel(const float* __restrict__ Opre0,
                                 const float* __restrict__ wo, const float* __restrict__ bo,
                                 const float* __restrict__ wk, const float* __restrict__ bk,
                                 const float* __restrict__ wv, const float* __restrict__ bv,
                                 float* __restrict__ K1, float* __restrict__ V1) {
    __shared__ float Ws[2][4096];
    __shared__ float As[32][65];
    __shared__ float Hs[32][65];
    int tid = threadIdx.x; // 256
    int row0 = blockIdx.x * 32;   // 160000 divisible by 32
    for (int k = tid; k < 4096; k += 256) Ws[0][k] = wo[k];
    for (int k = tid; k < 2048; k += 256) {
        int r = k >> 6, c = k & 63;
        As[r][c] = Opre0[(row0 + r) * 64 + c];
    }
    __syncthreads();
    int c = tid & 63, r0 = tid >> 6;
    float acc[8] = {};
    for (int k = 0; k < 64; ++k) {
        float w = Ws[0][k * 64 + c];
        #pragma unroll
        for (int rr = 0; rr < 8; ++rr) acc[rr] += As[r0 + rr * 4][k] * w;
    }
    float bb = bo[c];
    #pragma unroll
    for (int rr = 0; rr < 8; ++rr) {
        int r = r0 + rr * 4;
        float t = acc[rr] + bb;
        Hs[r][c] = As[r][c] + (t > 0.f ? t : 0.f);
    }
    __syncthreads();
    for (int k = tid; k < 4096; k += 256) { Ws[0][k] = wk[k]; Ws[1][k] = wv[k]; }
    __syncthreads();
    float acck[8] = {}, accv[8] = {};
    for (int k = 0; k < 64; ++k) {
        float wk_ = Ws[0][k * 64 + c], wv_ = Ws[1][k * 64 + c];
        #pragma unroll
        for (int rr = 0; rr < 8; ++rr) {
            float h = Hs[r0 + rr * 4][k];
            acck[rr] += h * wk_;
            accv[rr] += h * wv_;
        }
    }
    float bbk = bk[c], bbv = bv[c];
    #pragma unroll
    for (int rr = 0; rr < 8; ++rr) {
        int gr = row0 + r0 + rr * 4;
        K1[gr * 64 + c] = acck[rr] + bbk;
        V1[gr * 64 + c] = accv[rr] + bbv;
    }
}

// ===================== CSR build =====================
__global__ void hist_kernel(const int* __restrict__ edge, int* __restrict__ cnt) {
    int m = blockIdx.x * 256 + threadIdx.x;
    if (m < MINC) atomicAdd(&cnt[edge[m]], 1);
}

__global__ void scan_kernel(const int* __restrict__ cnt, int* __restrict__ rowstart,
                            int* __restrict__ cursor) {
    __shared__ int partial[1024];
    int tid = threadIdx.x;                       // 1024
    const int CH = (NEDGE + 1023) / 1024;        // 20
    int s = 0;
    for (int k = 0; k < CH; ++k) {
        int idx = tid * CH + k;
        if (idx < NEDGE) s += cnt[idx];
    }
    partial[tid] = s;
    __syncthreads();
    for (int off = 1; off < 1024; off <<= 1) {
        int v = 0;
        if (tid >= off) v = partial[tid - off];
        __syncthreads();
        if (tid >= off) partial[tid] += v;
        __syncthreads();
    }
    int base = (tid > 0) ? partial[tid - 1] : 0;
    for (int k = 0; k < CH; ++k) {
        int idx = tid * CH + k;
        if (idx < NEDGE) {
            rowstart[idx] = base;
            cursor[idx] = base;
            base += cnt[idx];
        }
    }
    if (tid == 1023) rowstart[NEDGE] = base;     // = MINC
}

__global__ void scatter_kernel(const int* __restrict__ node, const int* __restrict__ edge,
                               int* __restrict__ cursor, int* __restrict__ csr_node,
                               int* __restrict__ csr_m, int* __restrict__ csr_edge) {
    int m = blockIdx.x * 256 + threadIdx.x;
    if (m < MINC) {
        int e = edge[m];
        int pos = atomicAdd(&cursor[e], 1);
        csr_node[pos] = node[m];
        csr_m[pos] = m;
        csr_edge[pos] = e;
    }
}

// ===================== mab0 attention (score-prefused, no shuffles) =====================
// one wave per (edge, inducing point); lane = h*16+d
__global__ void attn0_kernel(const float* __restrict__ V0, const float* __restrict__ S0,
                             const float* __restrict__ QI,
                             const int* __restrict__ rowstart, const int* __restrict__ csr_node,
                             float* __restrict__ Opre0) {
    int w = blockIdx.x * 4 + (threadIdx.x >> 6); // 0..159999
    int e = w >> 3, i = w & 7;
    int lane = threadIdx.x & 63;
    int h = lane >> 4, d = lane & 15;
    int start = rowstart[e], end = rowstart[e + 1];
    float qi = QI[i * 64 + lane];
    float m_run = -INFINITY, l_run = 0.f, acc = 0.f;
    for (int p = start; p < end; ++p) {
        int n = csr_node[p];
        float s = S0[n * 32 + i * 4 + h];     // prefused, pre-scaled score
        float v = V0[n * 64 + lane];
        float m_new = fmaxf(m_run, s);
        float sc = __expf(m_run - m_new);
        float wexp = __expf(s - m_new);
        l_run = l_run * sc + wexp;
        acc = acc * sc + wexp * v;
        m_run = m_new;
    }
    float out = qi + ((l_run > 0.f) ? acc / l_run : 0.f);
    Opre0[(e * NIND + i) * 64 + d * 4 + h] = out;   // head-permuted layout
}

// ===================== mab1 attention (CSR order, DPP reduce) =====================
__global__ void attn1_kernel(const float* __restrict__ Q1, const float* __restrict__ K1,
                             const float* __restrict__ V1,
                             const int* __restrict__ csr_node, const int* __restrict__ csr_m,
                             const int* __restrict__ csr_edge,
                             float* __restrict__ Opre1) {
    int p = blockIdx.x * 4 + (threadIdx.x >> 6);
    if (p >= MINC) return;
    int lane = threadIdx.x & 63;
    int m = csr_m[p];
    int n = csr_node[p];
    int e = csr_edge[p];
    float q = Q1[n * 64 + lane];
    float a[8], v[8];
    #pragma unroll
    for (int i = 0; i < 8; ++i) {
        int row = e * NIND + i;
        a[i] = sum16(q * K1[row * 64 + lane]) * 0.125f;
        v[i] = V1[row * 64 + lane];
    }
    float mx = a[0];
    #pragma unroll
    for (int i = 1; i < 8; ++i) mx = fmaxf(mx, a[i]);
    float l = 0.f, acc = 0.f;
    #pragma unroll
    for (int i = 0; i < 8; ++i) {
        float w = __expf(a[i] - mx);
        l += w;
        acc += w * v[i];
    }
    float out = q + acc / l;
    Opre1[m * 64 + (lane & 15) * 4 + (lane >> 4)] = out;   // head-permuted layout
}

// ===================== host launch =====================
extern "C" void kernel_launch(void* const* d_in, const int* in_sizes, int n_in,
                              void* d_out, int out_size, void* d_ws, size_t ws_size,
                              hipStream_t stream) {
    const float* X    = (const float*)d_in[0];
    const int*   hei  = (const int*)d_in[1];       // [2, M]
    const float* I    = (const float*)d_in[2];
    const float* m0_wq = (const float*)d_in[3];
    const float* m0_bq = (const float*)d_in[4];
    const float* m0_wk = (const float*)d_in[5];
    const float* m0_bk = (const float*)d_in[6];
    const float* m0_wv = (const float*)d_in[7];
    const float* m0_bv = (const float*)d_in[8];
    const float* m0_wo = (const float*)d_in[9];
    const float* m0_bo = (const float*)d_in[10];
    const float* m1_wq = (const float*)d_in[11];
    const float* m1_bq = (const float*)d_in[12];
    const float* m1_wk = (const float*)d_in[13];
    const float* m1_bk = (const float*)d_in[14];
    const float* m1_wv = (const float*)d_in[15];
    const float* m1_bv = (const float*)d_in[16];
    const float* m1_wo = (const float*)d_in[17];
    const float* m1_bo = (const float*)d_in[18];

    const int* node = hei;           // [M]
    const int* edge = hei + MINC;    // [M]
    float* out = (float*)d_out;

    // -------- workspace layout (float offsets), lifetime-overlapped --------
    float* F = (float*)d_ws;
    float* Opre0 = F + 0;            // 10.24M  (attn0 -> fused_hkv)
    float* V0    = F + 10240000;     // 3.2M    (linear_dual -> attn0)
    float* S0    = F + 13440000;     // 1.6M    (linear_dual -> attn0)
    float* K1    = F + 15040000;     // 10.24M  (fused_hkv -> attn1)
    float* V1    = F + 25280000;     // 10.24M  (fused_hkv -> attn1)
    float* Q1    = F + 35520000;     // 3.2M    (linear -> attn1)
    float* Opre1 = F + 0;            // 12.8M   (attn1 -> final; aliases Opre0+V0, both dead)
    float* QI    = F + 38720000;     // 512
    float* Wf    = F + 38720512;     // 2048
    float* bf    = F + 38722560;     // 32
    int*   ib       = (int*)(F + 38722592);
    int*   rowstart = ib;                         // NE+1
    int*   cnt      = rowstart + (NEDGE + 1);     // NE
    int*   cursor   = cnt + NEDGE;                // NE
    int*   csr_node = cursor + NEDGE;             // M
    int*   csr_m    = csr_node + MINC;            // M
    int*   csr_edge = csr_m + MINC;               // M

    // ---------------- Phase A: mab0 ----------------
    qi_kernel<<<1, 512, 0, stream>>>(I, m0_wq, m0_bq, QI);
    fuse_kernel<<<1, 512, 0, stream>>>(QI, m0_wk, m0_bk, Wf, bf);
    linear_dual_kernel<<<(NNODES + 31) / 32, 256, 0, stream>>>(
        X, NNODES, m0_wv, m0_bv, V0, Wf, bf, S0);

    hipMemsetAsync(cnt, 0, NEDGE * sizeof(int), stream);
    hist_kernel<<<(MINC + 255) / 256, 256, 0, stream>>>(edge, cnt);
    scan_kernel<<<1, 1024, 0, stream>>>(cnt, rowstart, cursor);
    scatter_kernel<<<(MINC + 255) / 256, 256, 0, stream>>>(node, edge, cursor,
                                                           csr_node, csr_m, csr_edge);

    attn0_kernel<<<NEDGE * NIND / 4, 256, 0, stream>>>(V0, S0, QI, rowstart, csr_node, Opre0);

    // ---------------- Phase B: mab1 ----------------
    fused_hkv_kernel<<<NEDGE * NIND / 32, 256, 0, stream>>>(
        Opre0, m0_wo, m0_bo, m1_wk, m1_bk, m1_wv, m1_bv, K1, V1);
    linear_kernel<<<(NNODES + 31) / 32, 256, 0, stream>>>(X, NNODES, m1_wq, m1_bq, Q1);

    attn1_kernel<<<(MINC + 3) / 4, 256, 0, stream>>>(
        Q1, K1, V1, csr_node, csr_m, csr_edge, Opre1);
    linear_relu_res_kernel<<<MINC / 32, 256, 0, stream>>>(
        Opre1, MINC, m1_wo, m1_bo, out);
}

// Round 3
// 283.633 us; speedup vs baseline: 1.9964x; 1.8365x over previous
//
#include <hip/hip_runtime.h>
#include <math.h>

#define NNODES 50000
#define MINC   200000
#define NEDGE  20000
#define NIND   8

typedef __attribute__((ext_vector_type(8))) short bf16x8;
typedef __attribute__((ext_vector_type(4))) float f32x4;

// RNE float -> bf16 bits
__device__ __forceinline__ short f2bf(float f) {
    union { float f; unsigned u; } x; x.f = f;
    unsigned r = x.u + 0x7FFF + ((x.u >> 16) & 1);
    return (short)(r >> 16);
}
__device__ __forceinline__ float bf2f(short s) {
    union { unsigned u; float f; } x; x.u = ((unsigned)(unsigned short)s) << 16;
    return x.f;
}

// ---------- DPP 16-lane rotate-add reduction ----------
__device__ __forceinline__ float sum16(float x) {
    int v;
    v = __builtin_amdgcn_update_dpp(0, __float_as_int(x), 0x121, 0xf, 0xf, true);
    x += __int_as_float(v);
    v = __builtin_amdgcn_update_dpp(0, __float_as_int(x), 0x122, 0xf, 0xf, true);
    x += __int_as_float(v);
    v = __builtin_amdgcn_update_dpp(0, __float_as_int(x), 0x124, 0xf, 0xf, true);
    x += __int_as_float(v);
    v = __builtin_amdgcn_update_dpp(0, __float_as_int(x), 0x128, 0xf, 0xf, true);
    x += __int_as_float(v);
    return x;
}

// ===================== QI = I @ wq + bq  (8x64) =====================
__global__ void qi_kernel(const float* __restrict__ I, const float* __restrict__ wq,
                          const float* __restrict__ bq, float* __restrict__ QI) {
    int tid = threadIdx.x;            // 512
    int i = tid >> 6, c = tid & 63;
    float acc = bq[c];
    for (int k = 0; k < 64; ++k) acc += I[i * 64 + k] * wq[k * 64 + c];
    QI[i * 64 + c] = acc;
}

// ========= Wf[k, i*4+h] = 0.125 * sum_d wk[k, h*16+d] * QI[i, h*16+d] =========
__global__ void fuse_kernel(const float* __restrict__ QI, const float* __restrict__ wk,
                            const float* __restrict__ bk,
                            float* __restrict__ Wf, float* __restrict__ bfS) {
    int tid = threadIdx.x; // 512
    for (int idx = tid; idx < 2048; idx += 512) {
        int k = idx >> 5, j = idx & 31;
        int i = j >> 2, h = j & 3;
        float s = 0.f;
        for (int d = 0; d < 16; ++d)
            s += wk[k * 64 + h * 16 + d] * QI[i * 64 + h * 16 + d];
        Wf[idx] = s * 0.125f;
    }
    if (tid < 32) {
        int i = tid >> 2, h = tid & 3;
        float s = 0.f;
        for (int d = 0; d < 16; ++d)
            s += bk[h * 16 + d] * QI[i * 64 + h * 16 + d];
        bfS[tid] = s * 0.125f;
    }
}

// ====== pack 5 f32 [64][64] matrices into bf16 Wt[c][72] (transposed, padded) ======
__global__ void pack_kernel(const float* __restrict__ w0, const float* __restrict__ w1,
                            const float* __restrict__ w2, const float* __restrict__ w3,
                            const float* __restrict__ w4, short* __restrict__ dst) {
    const float* srcs[5] = {w0, w1, w2, w3, w4};
    const float* W = srcs[blockIdx.x];
    short* D = dst + blockIdx.x * 4608;
    int tid = threadIdx.x;  // 256
    for (int idx = tid; idx < 4096; idx += 256) {
        int c = idx >> 6, k = idx & 63;
        D[c * 72 + k] = f2bf(W[k * 64 + c]);
    }
    for (int idx = tid; idx < 512; idx += 256)
        D[(idx >> 3) * 72 + 64 + (idx & 7)] = 0;
}

// ====== pack [m0_wv | Wf] -> Wt0[96][72]; bias96 = [bv | bfS] ======
__global__ void pack_dual_kernel(const float* __restrict__ wv, const float* __restrict__ bv,
                                 const float* __restrict__ Wf, const float* __restrict__ bfS,
                                 short* __restrict__ D, float* __restrict__ bias96) {
    int tid = threadIdx.x; // 256
    for (int idx = tid; idx < 6144; idx += 256) {
        int c = idx >> 6, k = idx & 63;
        float v = (c < 64) ? wv[k * 64 + c] : Wf[k * 32 + (c - 64)];
        D[c * 72 + k] = f2bf(v);
    }
    for (int idx = tid; idx < 768; idx += 256)
        D[(idx >> 3) * 72 + 64 + (idx & 7)] = 0;
    if (tid < 96) bias96[tid] = (tid < 64) ? bv[tid] : bfS[tid - 64];
}

// =============== MFMA GEMM: C = A[N x 64] @ W[64 x NCOLS] + b ===============
// MODE 0: plain (NCOLS=96 splits cols 64.. into C1 with width 32)
// MODE 1: C0 = A + relu(A@W + b)
template<int NCOLS, int MODE>
__global__ void mfma_gemm_kernel(const float* __restrict__ A, int N,
                                 const short* __restrict__ Wt,
                                 const float* __restrict__ bias,
                                 float* __restrict__ C0, float* __restrict__ C1) {
    __shared__ short As[64 * 72];
    __shared__ short Ws[NCOLS * 72];
    int tid = threadIdx.x;     // 256
    int row0 = blockIdx.x * 64;
    {
        const uint4* wsrc = (const uint4*)Wt;
        uint4* wdst = (uint4*)Ws;
        for (int k = tid; k < NCOLS * 9; k += 256) wdst[k] = wsrc[k];
    }
    {
        int r = tid >> 2, c0 = (tid & 3) * 16;
        int gr = row0 + r;
        float f[16];
        if (gr < N) {
            const float4* src = (const float4*)(A + (size_t)gr * 64 + c0);
            #pragma unroll
            for (int j = 0; j < 4; ++j) {
                float4 t4 = src[j];
                f[4*j] = t4.x; f[4*j+1] = t4.y; f[4*j+2] = t4.z; f[4*j+3] = t4.w;
            }
        } else {
            #pragma unroll
            for (int j = 0; j < 16; ++j) f[j] = 0.f;
        }
        short tmp[16];
        #pragma unroll
        for (int j = 0; j < 16; ++j) tmp[j] = f2bf(f[j]);
        uint4* dst = (uint4*)&As[r * 72 + c0];
        dst[0] = *(const uint4*)&tmp[0];
        dst[1] = *(const uint4*)&tmp[8];
    }
    __syncthreads();
    constexpr int NT = NCOLS / 16;
    int w = tid >> 6, l = tid & 63;
    int lr16 = l & 15, lk = (l >> 4) * 8;
    f32x4 acc[NT] = {};
    #pragma unroll
    for (int ks = 0; ks < 2; ++ks) {
        bf16x8 a = *(const bf16x8*)&As[(w * 16 + lr16) * 72 + ks * 32 + lk];
        #pragma unroll
        for (int t = 0; t < NT; ++t) {
            bf16x8 b = *(const bf16x8*)&Ws[(t * 16 + lr16) * 72 + ks * 32 + lk];
            acc[t] = __builtin_amdgcn_mfma_f32_16x16x32_bf16(a, b, acc[t], 0, 0, 0);
        }
    }
    int rbase = w * 16 + (l >> 4) * 4;
    #pragma unroll
    for (int t = 0; t < NT; ++t) {
        int c = t * 16 + lr16;
        float bb = bias[c];
        #pragma unroll
        for (int r = 0; r < 4; ++r) {
            int gr = row0 + rbase + r;
            if (gr < N) {
                float val = acc[t][r] + bb;
                if constexpr (MODE == 1) {
                    float res = bf2f(As[(rbase + r) * 72 + c]);
                    C0[(size_t)gr * 64 + c] = res + fmaxf(val, 0.f);
                } else {
                    if constexpr (NCOLS == 96) {
                        if (c >= 64) { C1[(size_t)gr * 32 + (c - 64)] = val; continue; }
                    }
                    C0[(size_t)gr * 64 + c] = val;
                }
            }
        }
    }
}

// === fused: H = Opre0 + relu(Opre0@wo+bo) (LDS); K1 = H@wk+bk; V1 = H@wv+bv ===
__global__ void fused_hkv_mfma_kernel(const float* __restrict__ Opre0,
                                      const short* __restrict__ WtO, const float* __restrict__ bo,
                                      const short* __restrict__ WtK, const float* __restrict__ bk,
                                      const short* __restrict__ WtV, const float* __restrict__ bv,
                                      float* __restrict__ K1, float* __restrict__ V1) {
    __shared__ short As[64 * 72];
    __shared__ short Hs[64 * 72];
    __shared__ short Wo[64 * 72];
    __shared__ short Wk[64 * 72];
    __shared__ short Wv[64 * 72];
    int tid = threadIdx.x;   // 256
    int row0 = blockIdx.x * 64;   // 160000 % 64 == 0
    {
        uint4* d0 = (uint4*)Wo; const uint4* s0 = (const uint4*)WtO;
        uint4* d1 = (uint4*)Wk; const uint4* s1 = (const uint4*)WtK;
        uint4* d2 = (uint4*)Wv; const uint4* s2 = (const uint4*)WtV;
        for (int k = tid; k < 576; k += 256) { d0[k] = s0[k]; d1[k] = s1[k]; d2[k] = s2[k]; }
    }
    {
        int r = tid >> 2, c0 = (tid & 3) * 16;
        const float4* src = (const float4*)(Opre0 + (size_t)(row0 + r) * 64 + c0);
        float f[16];
        #pragma unroll
        for (int j = 0; j < 4; ++j) {
            float4 t4 = src[j];
            f[4*j] = t4.x; f[4*j+1] = t4.y; f[4*j+2] = t4.z; f[4*j+3] = t4.w;
        }
        short tmp[16];
        #pragma unroll
        for (int j = 0; j < 16; ++j) tmp[j] = f2bf(f[j]);
        uint4* dst = (uint4*)&As[r * 72 + c0];
        dst[0] = *(const uint4*)&tmp[0];
        dst[1] = *(const uint4*)&tmp[8];
    }
    __syncthreads();
    int w = tid >> 6, l = tid & 63;
    int lr16 = l & 15, lk = (l >> 4) * 8;
    int rbase = w * 16 + (l >> 4) * 4;
    // GEMM1: Opre0 @ wo
    {
        f32x4 acc[4] = {};
        #pragma unroll
        for (int ks = 0; ks < 2; ++ks) {
            bf16x8 a = *(const bf16x8*)&As[(w * 16 + lr16) * 72 + ks * 32 + lk];
            #pragma unroll
            for (int t = 0; t < 4; ++t) {
                bf16x8 b = *(const bf16x8*)&Wo[(t * 16 + lr16) * 72 + ks * 32 + lk];
                acc[t] = __builtin_amdgcn_mfma_f32_16x16x32_bf16(a, b, acc[t], 0, 0, 0);
            }
        }
        #pragma unroll
        for (int t = 0; t < 4; ++t) {
            int c = t * 16 + lr16;
            float bb = bo[c];
            #pragma unroll
            for (int r = 0; r < 4; ++r) {
                float res = bf2f(As[(rbase + r) * 72 + c]);
                float hv = res + fmaxf(acc[t][r] + bb, 0.f);
                Hs[(rbase + r) * 72 + c] = f2bf(hv);
            }
        }
    }
    __syncthreads();
    // GEMM2+3: H @ wk, H @ wv
    {
        f32x4 ak[4] = {}, av[4] = {};
        #pragma unroll
        for (int ks = 0; ks < 2; ++ks) {
            bf16x8 a = *(const bf16x8*)&Hs[(w * 16 + lr16) * 72 + ks * 32 + lk];
            #pragma unroll
            for (int t = 0; t < 4; ++t) {
                bf16x8 b1 = *(const bf16x8*)&Wk[(t * 16 + lr16) * 72 + ks * 32 + lk];
                ak[t] = __builtin_amdgcn_mfma_f32_16x16x32_bf16(a, b1, ak[t], 0, 0, 0);
                bf16x8 b2 = *(const bf16x8*)&Wv[(t * 16 + lr16) * 72 + ks * 32 + lk];
                av[t] = __builtin_amdgcn_mfma_f32_16x16x32_bf16(a, b2, av[t], 0, 0, 0);
            }
        }
        #pragma unroll
        for (int t = 0; t < 4; ++t) {
            int c = t * 16 + lr16;
            float bbk = bk[c], bbv = bv[c];
            #pragma unroll
            for (int r = 0; r < 4; ++r) {
                size_t gr = (size_t)(row0 + rbase + r);
                K1[gr * 64 + c] = ak[t][r] + bbk;
                V1[gr * 64 + c] = av[t][r] + bbv;
            }
        }
    }
}

// ===================== CSR build =====================
__global__ void hist_kernel(const int* __restrict__ edge, int* __restrict__ cnt) {
    int m = blockIdx.x * 256 + threadIdx.x;
    if (m < MINC) atomicAdd(&cnt[edge[m]], 1);
}

__global__ void scan_kernel(const int* __restrict__ cnt, int* __restrict__ rowstart,
                            int* __restrict__ cursor) {
    __shared__ int partial[1024];
    int tid = threadIdx.x;                       // 1024
    const int CH = (NEDGE + 1023) / 1024;        // 20
    int s = 0;
    for (int k = 0; k < CH; ++k) {
        int idx = tid * CH + k;
        if (idx < NEDGE) s += cnt[idx];
    }
    partial[tid] = s;
    __syncthreads();
    for (int off = 1; off < 1024; off <<= 1) {
        int v = 0;
        if (tid >= off) v = partial[tid - off];
        __syncthreads();
        if (tid >= off) partial[tid] += v;
        __syncthreads();
    }
    int base = (tid > 0) ? partial[tid - 1] : 0;
    for (int k = 0; k < CH; ++k) {
        int idx = tid * CH + k;
        if (idx < NEDGE) {
            rowstart[idx] = base;
            cursor[idx] = base;
            base += cnt[idx];
        }
    }
    if (tid == 1023) rowstart[NEDGE] = base;
}

__global__ void scatter_kernel(const int* __restrict__ node, const int* __restrict__ edge,
                               int* __restrict__ cursor, int* __restrict__ csr_node,
                               int* __restrict__ csr_m, int* __restrict__ csr_edge) {
    int m = blockIdx.x * 256 + threadIdx.x;
    if (m < MINC) {
        int e = edge[m];
        int pos = atomicAdd(&cursor[e], 1);
        csr_node[pos] = node[m];
        csr_m[pos] = m;
        csr_edge[pos] = e;
    }
}

// ============ mab0 attention: block per edge, LDS-staged V0/S0 ============
__global__ void attn0_kernel(const float* __restrict__ V0, const float* __restrict__ S0,
                             const float* __restrict__ QI,
                             const int* __restrict__ rowstart, const int* __restrict__ csr_node,
                             float* __restrict__ Opre0) {
    __shared__ float Vs[32][64];
    __shared__ float Ss[32][32];
    int e = blockIdx.x;
    int tid = threadIdx.x;        // 512
    int i = tid >> 6, lane = tid & 63;
    int h = lane >> 4, d = lane & 15;
    int start = rowstart[e], end = rowstart[e + 1];
    float qi = QI[i * 64 + lane];
    float m_run = -INFINITY, l_run = 0.f, acc = 0.f;
    for (int c0 = start; c0 < end; c0 += 32) {
        int cnt = min(32, end - c0);
        __syncthreads();
        for (int idx = tid; idx < cnt * 64; idx += 512) {
            int r = idx >> 6, col = idx & 63;
            int n = csr_node[c0 + r];
            Vs[r][col] = V0[(size_t)n * 64 + col];
        }
        for (int idx = tid; idx < cnt * 32; idx += 512) {
            int r = idx >> 5, col = idx & 31;
            int n = csr_node[c0 + r];
            Ss[r][col] = S0[(size_t)n * 32 + col];
        }
        __syncthreads();
        for (int p = 0; p < cnt; ++p) {
            float s = Ss[p][i * 4 + h];
            float v = Vs[p][lane];
            float m_new = fmaxf(m_run, s);
            float sc = __expf(m_run - m_new);
            float wexp = __expf(s - m_new);
            l_run = l_run * sc + wexp;
            acc = acc * sc + wexp * v;
            m_run = m_new;
        }
    }
    float out = qi + ((l_run > 0.f) ? acc / l_run : 0.f);
    Opre0[(size_t)(e * NIND + i) * 64 + d * 4 + h] = out;   // head-permuted
}

// ===================== mab1 attention (CSR order, DPP reduce) =====================
__global__ void attn1_kernel(const float* __restrict__ Q1, const float* __restrict__ K1,
                             const float* __restrict__ V1,
                             const int* __restrict__ csr_node, const int* __restrict__ csr_m,
                             const int* __restrict__ csr_edge,
                             float* __restrict__ Opre1) {
    int p = blockIdx.x * 4 + (threadIdx.x >> 6);
    if (p >= MINC) return;
    int lane = threadIdx.x & 63;
    int m = csr_m[p];
    int n = csr_node[p];
    int e = csr_edge[p];
    float q = Q1[(size_t)n * 64 + lane];
    float a[8], v[8];
    #pragma unroll
    for (int i = 0; i < 8; ++i) {
        size_t row = (size_t)(e * NIND + i);
        a[i] = sum16(q * K1[row * 64 + lane]) * 0.125f;
        v[i] = V1[row * 64 + lane];
    }
    float mx = a[0];
    #pragma unroll
    for (int i = 1; i < 8; ++i) mx = fmaxf(mx, a[i]);
    float l = 0.f, acc = 0.f;
    #pragma unroll
    for (int i = 0; i < 8; ++i) {
        float w = __expf(a[i] - mx);
        l += w;
        acc += w * v[i];
    }
    float out = q + acc / l;
    Opre1[(size_t)m * 64 + (lane & 15) * 4 + (lane >> 4)] = out;
}

// ===================== host launch =====================
extern "C" void kernel_launch(void* const* d_in, const int* in_sizes, int n_in,
                              void* d_out, int out_size, void* d_ws, size_t ws_size,
                              hipStream_t stream) {
    const float* X    = (const float*)d_in[0];
    const int*   hei  = (const int*)d_in[1];
    const float* I    = (const float*)d_in[2];
    const float* m0_wq = (const float*)d_in[3];
    const float* m0_bq = (const float*)d_in[4];
    const float* m0_wk = (const float*)d_in[5];
    const float* m0_bk = (const float*)d_in[6];
    const float* m0_wv = (const float*)d_in[7];
    const float* m0_bv = (const float*)d_in[8];
    const float* m0_wo = (const float*)d_in[9];
    const float* m0_bo = (const float*)d_in[10];
    const float* m1_wq = (const float*)d_in[11];
    const float* m1_bq = (const float*)d_in[12];
    const float* m1_wk = (const float*)d_in[13];
    const float* m1_bk = (const float*)d_in[14];
    const float* m1_wv = (const float*)d_in[15];
    const float* m1_bv = (const float*)d_in[16];
    const float* m1_wo = (const float*)d_in[17];
    const float* m1_bo = (const float*)d_in[18];

    const int* node = hei;           // [M]
    const int* edge = hei + MINC;    // [M]
    float* out = (float*)d_out;

    // -------- workspace layout (float offsets) --------
    float* F = (float*)d_ws;
    float* Opre0 = F + 0;            // 10.24M (attn0 -> fused_hkv)
    float* Opre1 = F + 0;            // 12.8M  (aliases Opre0+V0 later, both dead)
    float* V0    = F + 12800000;     // 3.2M
    float* S0    = F + 16000000;     // 1.6M
    float* K1    = F + 17600000;     // 10.24M
    float* V1    = F + 27840000;     // 10.24M
    float* Q1    = F + 38080000;     // 3.2M
    float* QI    = F + 41280000;     // 512
    float* Wf    = F + 41280512;     // 2048
    float* bfS   = F + 41282560;     // 32
    float* bias96 = F + 41282592;    // 96
    short* PK    = (short*)(F + 41282688);   // packed weights: 29952 shorts
    short* WtO   = PK + 0;
    short* WtK   = PK + 4608;
    short* WtV   = PK + 9216;
    short* WtQ   = PK + 13824;
    short* WtF   = PK + 18432;
    short* Wt0   = PK + 23040;       // 96x72
    int*   ib       = (int*)(F + 41297700);
    int*   rowstart = ib;                         // NE+1
    int*   cnt      = rowstart + (NEDGE + 1);     // NE
    int*   cursor   = cnt + NEDGE;                // NE
    int*   csr_node = cursor + NEDGE;             // M
    int*   csr_m    = csr_node + MINC;            // M
    int*   csr_edge = csr_m + MINC;               // M

    // ---------------- setup ----------------
    qi_kernel<<<1, 512, 0, stream>>>(I, m0_wq, m0_bq, QI);
    fuse_kernel<<<1, 512, 0, stream>>>(QI, m0_wk, m0_bk, Wf, bfS);
    pack_kernel<<<5, 256, 0, stream>>>(m0_wo, m1_wk, m1_wv, m1_wq, m1_wo, PK);
    pack_dual_kernel<<<1, 256, 0, stream>>>(m0_wv, m0_bv, Wf, bfS, Wt0, bias96);

    hipMemsetAsync(cnt, 0, NEDGE * sizeof(int), stream);
    hist_kernel<<<(MINC + 255) / 256, 256, 0, stream>>>(edge, cnt);
    scan_kernel<<<1, 1024, 0, stream>>>(cnt, rowstart, cursor);
    scatter_kernel<<<(MINC + 255) / 256, 256, 0, stream>>>(node, edge, cursor,
                                                           csr_node, csr_m, csr_edge);

    // ---------------- Phase A: mab0 ----------------
    mfma_gemm_kernel<96, 0><<<(NNODES + 63) / 64, 256, 0, stream>>>(
        X, NNODES, Wt0, bias96, V0, S0);
    attn0_kernel<<<NEDGE, 512, 0, stream>>>(V0, S0, QI, rowstart, csr_node, Opre0);

    // ---------------- Phase B: mab1 ----------------
    fused_hkv_mfma_kernel<<<NEDGE * NIND / 64, 256, 0, stream>>>(
        Opre0, WtO, m0_bo, WtK, m1_bk, WtV, m1_bv, K1, V1);
    mfma_gemm_kernel<64, 0><<<(NNODES + 63) / 64, 256, 0, stream>>>(
        X, NNODES, WtQ, m1_bq, Q1, nullptr);
    attn1_kernel<<<(MINC + 3) / 4, 256, 0, stream>>>(
        Q1, K1, V1, csr_node, csr_m, csr_edge, Opre1);
    mfma_gemm_kernel<64, 1><<<(MINC + 63) / 64, 256, 0, stream>>>(
        Opre1, MINC, WtF, m1_bo, out, nullptr);
}

// Round 4
// 247.476 us; speedup vs baseline: 2.2880x; 1.1461x over previous
//
#include <hip/hip_runtime.h>
#include <math.h>

#define NNODES 50000
#define MINC   200000
#define NEDGE  20000
#define NIND   8

typedef __attribute__((ext_vector_type(8))) short bf16x8;
typedef __attribute__((ext_vector_type(4))) float f32x4;

__device__ __forceinline__ short f2bf(float f) {
    union { float f; unsigned u; } x; x.f = f;
    unsigned r = x.u + 0x7FFF + ((x.u >> 16) & 1);
    return (short)(r >> 16);
}
__device__ __forceinline__ float bf2f(short s) {
    union { unsigned u; float f; } x; x.u = ((unsigned)(unsigned short)s) << 16;
    return x.f;
}

// ---------- DPP 16-lane rotate-add reduction ----------
__device__ __forceinline__ float sum16(float x) {
    int v;
    v = __builtin_amdgcn_update_dpp(0, __float_as_int(x), 0x121, 0xf, 0xf, true);
    x += __int_as_float(v);
    v = __builtin_amdgcn_update_dpp(0, __float_as_int(x), 0x122, 0xf, 0xf, true);
    x += __int_as_float(v);
    v = __builtin_amdgcn_update_dpp(0, __float_as_int(x), 0x124, 0xf, 0xf, true);
    x += __int_as_float(v);
    v = __builtin_amdgcn_update_dpp(0, __float_as_int(x), 0x128, 0xf, 0xf, true);
    x += __int_as_float(v);
    return x;
}

// ===================== QI = I @ wq + bq  (8x64) =====================
__global__ void qi_kernel(const float* __restrict__ I, const float* __restrict__ wq,
                          const float* __restrict__ bq, float* __restrict__ QI) {
    int tid = threadIdx.x;            // 512
    int i = tid >> 6, c = tid & 63;
    float acc = bq[c];
    for (int k = 0; k < 64; ++k) acc += I[i * 64 + k] * wq[k * 64 + c];
    QI[i * 64 + c] = acc;
}

// ========= Wf[k, i*4+h] = 0.125 * sum_d wk[k, h*16+d] * QI[i, h*16+d] =========
__global__ void fuse_kernel(const float* __restrict__ QI, const float* __restrict__ wk,
                            const float* __restrict__ bk,
                            float* __restrict__ Wf, float* __restrict__ bfS) {
    int tid = threadIdx.x; // 512
    for (int idx = tid; idx < 2048; idx += 512) {
        int k = idx >> 5, j = idx & 31;
        int i = j >> 2, h = j & 3;
        float s = 0.f;
        for (int d = 0; d < 16; ++d)
            s += wk[k * 64 + h * 16 + d] * QI[i * 64 + h * 16 + d];
        Wf[idx] = s * 0.125f;
    }
    if (tid < 32) {
        int i = tid >> 2, h = tid & 3;
        float s = 0.f;
        for (int d = 0; d < 16; ++d)
            s += bk[h * 16 + d] * QI[i * 64 + h * 16 + d];
        bfS[tid] = s * 0.125f;
    }
}

// ====== pack 5 f32 [64][64] matrices into bf16 Wt[c][72] (transposed, padded) ======
__global__ void pack_kernel(const float* __restrict__ w0, const float* __restrict__ w1,
                            const float* __restrict__ w2, const float* __restrict__ w3,
                            const float* __restrict__ w4, short* __restrict__ dst) {
    const float* srcs[5] = {w0, w1, w2, w3, w4};
    const float* W = srcs[blockIdx.x];
    short* D = dst + blockIdx.x * 4608;
    int tid = threadIdx.x;  // 256
    for (int idx = tid; idx < 4096; idx += 256) {
        int c = idx >> 6, k = idx & 63;
        D[c * 72 + k] = f2bf(W[k * 64 + c]);
    }
    for (int idx = tid; idx < 512; idx += 256)
        D[(idx >> 3) * 72 + 64 + (idx & 7)] = 0;
}

// ====== pack [m0_wv | Wf] -> Wt0[96][72]; bias96 = [bv | bfS] ======
__global__ void pack_dual_kernel(const float* __restrict__ wv, const float* __restrict__ bv,
                                 const float* __restrict__ Wf, const float* __restrict__ bfS,
                                 short* __restrict__ D, float* __restrict__ bias96) {
    int tid = threadIdx.x; // 256
    for (int idx = tid; idx < 6144; idx += 256) {
        int c = idx >> 6, k = idx & 63;
        float v = (c < 64) ? wv[k * 64 + c] : Wf[k * 32 + (c - 64)];
        D[c * 72 + k] = f2bf(v);
    }
    for (int idx = tid; idx < 768; idx += 256)
        D[(idx >> 3) * 72 + 64 + (idx & 7)] = 0;
    if (tid < 96) bias96[tid] = (tid < 64) ? bv[tid] : bfS[tid - 64];
}

// =============== MFMA GEMM: C = A[N x 64] @ W[64 x NCOLS] + b ===============
// MODE 0: A f32; C0 bf16 (cols<64), C1 f32 width 32 (cols>=64, NCOLS=96)
// MODE 1: A bf16; C0 f32 = A + relu(A@W + b)
// MODE 2: A f32; C0 bf16
template<int NCOLS, int MODE>
__global__ void mfma_gemm_kernel(const void* __restrict__ Av, int N,
                                 const short* __restrict__ Wt,
                                 const float* __restrict__ bias,
                                 void* __restrict__ C0v, float* __restrict__ C1) {
    __shared__ short As[64 * 72];
    __shared__ short Ws[NCOLS * 72];
    int tid = threadIdx.x;     // 256
    int row0 = blockIdx.x * 64;
    {
        const uint4* wsrc = (const uint4*)Wt;
        uint4* wdst = (uint4*)Ws;
        for (int k = tid; k < NCOLS * 9; k += 256) wdst[k] = wsrc[k];
    }
    {
        int r = tid >> 2, c0 = (tid & 3) * 16;
        int gr = row0 + r;
        uint4* dst = (uint4*)&As[r * 72 + c0];
        if constexpr (MODE == 1) {
            uint4 a0 = {}, a1 = {};
            if (gr < N) {
                const uint4* src = (const uint4*)((const short*)Av + (size_t)gr * 64 + c0);
                a0 = src[0]; a1 = src[1];
            }
            dst[0] = a0; dst[1] = a1;
        } else {
            float f[16];
            if (gr < N) {
                const float4* src = (const float4*)((const float*)Av + (size_t)gr * 64 + c0);
                #pragma unroll
                for (int j = 0; j < 4; ++j) {
                    float4 t4 = src[j];
                    f[4*j] = t4.x; f[4*j+1] = t4.y; f[4*j+2] = t4.z; f[4*j+3] = t4.w;
                }
            } else {
                #pragma unroll
                for (int j = 0; j < 16; ++j) f[j] = 0.f;
            }
            short tmp[16];
            #pragma unroll
            for (int j = 0; j < 16; ++j) tmp[j] = f2bf(f[j]);
            dst[0] = *(const uint4*)&tmp[0];
            dst[1] = *(const uint4*)&tmp[8];
        }
    }
    __syncthreads();
    constexpr int NT = NCOLS / 16;
    int w = tid >> 6, l = tid & 63;
    int lr16 = l & 15, lk = (l >> 4) * 8;
    f32x4 acc[NT] = {};
    #pragma unroll
    for (int ks = 0; ks < 2; ++ks) {
        bf16x8 a = *(const bf16x8*)&As[(w * 16 + lr16) * 72 + ks * 32 + lk];
        #pragma unroll
        for (int t = 0; t < NT; ++t) {
            bf16x8 b = *(const bf16x8*)&Ws[(t * 16 + lr16) * 72 + ks * 32 + lk];
            acc[t] = __builtin_amdgcn_mfma_f32_16x16x32_bf16(a, b, acc[t], 0, 0, 0);
        }
    }
    int rbase = w * 16 + (l >> 4) * 4;
    #pragma unroll
    for (int t = 0; t < NT; ++t) {
        int c = t * 16 + lr16;
        float bb = bias[c];
        #pragma unroll
        for (int r = 0; r < 4; ++r) {
            int gr = row0 + rbase + r;
            if (gr < N) {
                float val = acc[t][r] + bb;
                if constexpr (MODE == 1) {
                    float res = bf2f(As[(rbase + r) * 72 + c]);
                    ((float*)C0v)[(size_t)gr * 64 + c] = res + fmaxf(val, 0.f);
                } else if constexpr (MODE == 0) {
                    if (c >= 64) ((float*)C1)[(size_t)gr * 32 + (c - 64)] = val;
                    else ((short*)C0v)[(size_t)gr * 64 + c] = f2bf(val);
                } else {
                    ((short*)C0v)[(size_t)gr * 64 + c] = f2bf(val);
                }
            }
        }
    }
}

// === fused: H = Opre0 + relu(Opre0@wo+bo) (LDS); K1 = H@wk+bk; V1 = H@wv+bv ===
__global__ void fused_hkv_mfma_kernel(const short* __restrict__ Opre0,
                                      const short* __restrict__ WtO, const float* __restrict__ bo,
                                      const short* __restrict__ WtK, const float* __restrict__ bk,
                                      const short* __restrict__ WtV, const float* __restrict__ bv,
                                      short* __restrict__ K1, short* __restrict__ V1) {
    __shared__ short As[64 * 72];
    __shared__ short Hs[64 * 72];
    __shared__ short Wo[64 * 72];
    __shared__ short Wk[64 * 72];
    __shared__ short Wv[64 * 72];
    int tid = threadIdx.x;   // 256
    int row0 = blockIdx.x * 64;   // 160000 % 64 == 0
    {
        uint4* d0 = (uint4*)Wo; const uint4* s0 = (const uint4*)WtO;
        uint4* d1 = (uint4*)Wk; const uint4* s1 = (const uint4*)WtK;
        uint4* d2 = (uint4*)Wv; const uint4* s2 = (const uint4*)WtV;
        for (int k = tid; k < 576; k += 256) { d0[k] = s0[k]; d1[k] = s1[k]; d2[k] = s2[k]; }
    }
    {
        int r = tid >> 2, c0 = (tid & 3) * 16;
        const uint4* src = (const uint4*)(Opre0 + (size_t)(row0 + r) * 64 + c0);
        uint4* dst = (uint4*)&As[r * 72 + c0];
        dst[0] = src[0]; dst[1] = src[1];
    }
    __syncthreads();
    int w = tid >> 6, l = tid & 63;
    int lr16 = l & 15, lk = (l >> 4) * 8;
    int rbase = w * 16 + (l >> 4) * 4;
    {
        f32x4 acc[4] = {};
        #pragma unroll
        for (int ks = 0; ks < 2; ++ks) {
            bf16x8 a = *(const bf16x8*)&As[(w * 16 + lr16) * 72 + ks * 32 + lk];
            #pragma unroll
            for (int t = 0; t < 4; ++t) {
                bf16x8 b = *(const bf16x8*)&Wo[(t * 16 + lr16) * 72 + ks * 32 + lk];
                acc[t] = __builtin_amdgcn_mfma_f32_16x16x32_bf16(a, b, acc[t], 0, 0, 0);
            }
        }
        #pragma unroll
        for (int t = 0; t < 4; ++t) {
            int c = t * 16 + lr16;
            float bb = bo[c];
            #pragma unroll
            for (int r = 0; r < 4; ++r) {
                float res = bf2f(As[(rbase + r) * 72 + c]);
                float hv = res + fmaxf(acc[t][r] + bb, 0.f);
                Hs[(rbase + r) * 72 + c] = f2bf(hv);
            }
        }
    }
    __syncthreads();
    {
        f32x4 ak[4] = {}, av[4] = {};
        #pragma unroll
        for (int ks = 0; ks < 2; ++ks) {
            bf16x8 a = *(const bf16x8*)&Hs[(w * 16 + lr16) * 72 + ks * 32 + lk];
            #pragma unroll
            for (int t = 0; t < 4; ++t) {
                bf16x8 b1 = *(const bf16x8*)&Wk[(t * 16 + lr16) * 72 + ks * 32 + lk];
                ak[t] = __builtin_amdgcn_mfma_f32_16x16x32_bf16(a, b1, ak[t], 0, 0, 0);
                bf16x8 b2 = *(const bf16x8*)&Wv[(t * 16 + lr16) * 72 + ks * 32 + lk];
                av[t] = __builtin_amdgcn_mfma_f32_16x16x32_bf16(a, b2, av[t], 0, 0, 0);
            }
        }
        #pragma unroll
        for (int t = 0; t < 4; ++t) {
            int c = t * 16 + lr16;
            float bbk = bk[c], bbv = bv[c];
            #pragma unroll
            for (int r = 0; r < 4; ++r) {
                size_t gr = (size_t)(row0 + rbase + r);
                K1[gr * 64 + c] = f2bf(ak[t][r] + bbk);
                V1[gr * 64 + c] = f2bf(av[t][r] + bbv);
            }
        }
    }
}

// ===================== CSR build =====================
__global__ void hist_kernel(const int* __restrict__ edge, int* __restrict__ cnt) {
    int m = blockIdx.x * 256 + threadIdx.x;
    if (m < MINC) atomicAdd(&cnt[edge[m]], 1);
}

__global__ void scan_kernel(const int* __restrict__ cnt, int* __restrict__ rowstart,
                            int* __restrict__ cursor) {
    __shared__ int partial[1024];
    int tid = threadIdx.x;                       // 1024
    const int CH = (NEDGE + 1023) / 1024;        // 20
    int s = 0;
    for (int k = 0; k < CH; ++k) {
        int idx = tid * CH + k;
        if (idx < NEDGE) s += cnt[idx];
    }
    partial[tid] = s;
    __syncthreads();
    for (int off = 1; off < 1024; off <<= 1) {
        int v = 0;
        if (tid >= off) v = partial[tid - off];
        __syncthreads();
        if (tid >= off) partial[tid] += v;
        __syncthreads();
    }
    int base = (tid > 0) ? partial[tid - 1] : 0;
    for (int k = 0; k < CH; ++k) {
        int idx = tid * CH + k;
        if (idx < NEDGE) {
            rowstart[idx] = base;
            cursor[idx] = base;
            base += cnt[idx];
        }
    }
    if (tid == 1023) rowstart[NEDGE] = base;
}

__global__ void scatter_kernel(const int* __restrict__ node, const int* __restrict__ edge,
                               int* __restrict__ cursor, int* __restrict__ csr_node,
                               int* __restrict__ csr_m) {
    int m = blockIdx.x * 256 + threadIdx.x;
    if (m < MINC) {
        int e = edge[m];
        int pos = atomicAdd(&cursor[e], 1);
        csr_node[pos] = node[m];
        csr_m[pos] = m;
    }
}

// ============ mab0 attention: ONE WAVE PER EDGE, two-phase ============
// Phase 1 (lane = pslot*32 + j, j=i*4+h): load scores, chunk max, exp weights
//   stored transposed in LDS Sw[p][h*8+i].
// Phase 2 (lane = h*16+d): acc[i] += w[i]*V[p][lane], V read once per row.
#define CH0 32
__global__ void attn0_kernel(const short* __restrict__ V0, const float* __restrict__ S0,
                             const float* __restrict__ QI,
                             const int* __restrict__ rowstart, const int* __restrict__ csr_node,
                             short* __restrict__ Opre0) {
    __shared__ float Sw[4][CH0][32];
    __shared__ float Sc[4][32];
    __shared__ float Li[4][32];
    int w = threadIdx.x >> 6;
    int lane = threadIdx.x & 63;
    int e = blockIdx.x * 4 + w;
    int start = rowstart[e], end = rowstart[e + 1];
    // phase-1 mapping
    int j = lane & 31;                       // i*4+h
    int pslot = lane >> 5;
    int tj = ((j & 3) << 3) | (j >> 2);      // h*8+i
    // phase-2 mapping
    int h2 = lane >> 4, d2 = lane & 15;
    float runm = -INFINITY, lrun = 0.f;
    float acc[8] = {};
    for (int c0 = start; c0 < end; c0 += CH0) {
        int cnt = min(CH0, end - c0);
        // ---- phase 1a: scores + chunk max ----
        float cm = -INFINITY;
        for (int p = pslot; p < cnt; p += 2) {
            int n = csr_node[c0 + p];
            float s = S0[(size_t)n * 32 + j];
            Sw[w][p][tj] = s;
            cm = fmaxf(cm, s);
        }
        cm = fmaxf(cm, __shfl_xor(cm, 32));
        float newm = fmaxf(runm, cm);
        float sc = __expf(runm - newm);      // 0 on first chunk
        runm = newm;
        // ---- phase 1b: exp weights + partial l ----
        float lsum = 0.f;
        for (int p = pslot; p < cnt; p += 2) {
            float s = Sw[w][p][tj];
            float w_ = __expf(s - newm);
            Sw[w][p][tj] = w_;
            lsum += w_;
        }
        lsum += __shfl_xor(lsum, 32);
        lrun = lrun * sc + lsum;
        if (pslot == 0) Sc[w][tj] = sc;
        // wave-internal LDS visibility (lockstep wave, uniform loops)
        asm volatile("s_waitcnt lgkmcnt(0)" ::: "memory");
        __builtin_amdgcn_sched_barrier(0);
        // ---- phase 2: PV accumulate ----
        float4 sA = *(const float4*)&Sc[w][h2 * 8];
        float4 sB = *(const float4*)&Sc[w][h2 * 8 + 4];
        acc[0] *= sA.x; acc[1] *= sA.y; acc[2] *= sA.z; acc[3] *= sA.w;
        acc[4] *= sB.x; acc[5] *= sB.y; acc[6] *= sB.z; acc[7] *= sB.w;
        for (int p = 0; p < cnt; ++p) {
            int n = csr_node[c0 + p];
            float v = bf2f(V0[(size_t)n * 64 + lane]);
            float4 wA = *(const float4*)&Sw[w][p][h2 * 8];
            float4 wB = *(const float4*)&Sw[w][p][h2 * 8 + 4];
            acc[0] += wA.x * v; acc[1] += wA.y * v; acc[2] += wA.z * v; acc[3] += wA.w * v;
            acc[4] += wB.x * v; acc[5] += wB.y * v; acc[6] += wB.z * v; acc[7] += wB.w * v;
        }
    }
    if (pslot == 0) Li[w][tj] = lrun;
    asm volatile("s_waitcnt lgkmcnt(0)" ::: "memory");
    __builtin_amdgcn_sched_barrier(0);
    float4 lA = *(const float4*)&Li[w][h2 * 8];
    float4 lB = *(const float4*)&Li[w][h2 * 8 + 4];
    float li[8] = {lA.x, lA.y, lA.z, lA.w, lB.x, lB.y, lB.z, lB.w};
    #pragma unroll
    for (int i = 0; i < 8; ++i) {
        float qi = QI[i * 64 + lane];
        float o = qi + ((li[i] > 0.f) ? acc[i] / li[i] : 0.f);
        Opre0[(size_t)(e * NIND + i) * 64 + d2 * 4 + h2] = f2bf(o);
    }
}

// ===================== mab1 attention: ONE WAVE PER EDGE =====================
__global__ void attn1_kernel(const short* __restrict__ Q1, const short* __restrict__ K1,
                             const short* __restrict__ V1,
                             const int* __restrict__ rowstart, const int* __restrict__ csr_node,
                             const int* __restrict__ csr_m,
                             short* __restrict__ Opre1) {
    int w = threadIdx.x >> 6;
    int lane = threadIdx.x & 63;
    int e = blockIdx.x * 4 + w;
    float K[8], V[8];
    #pragma unroll
    for (int i = 0; i < 8; ++i) {
        size_t row = (size_t)(e * NIND + i) * 64 + lane;
        K[i] = bf2f(K1[row]);
        V[i] = bf2f(V1[row]);
    }
    int start = rowstart[e], end = rowstart[e + 1];
    int oc = (lane & 15) * 4 + (lane >> 4);     // permuted output column
    for (int p = start; p < end; ++p) {
        int n = csr_node[p];
        int m = csr_m[p];
        float q = bf2f(Q1[(size_t)n * 64 + lane]);
        float a[8];
        #pragma unroll
        for (int i = 0; i < 8; ++i) a[i] = sum16(q * K[i]) * 0.125f;
        float mx = a[0];
        #pragma unroll
        for (int i = 1; i < 8; ++i) mx = fmaxf(mx, a[i]);
        float l = 0.f, acc = 0.f;
        #pragma unroll
        for (int i = 0; i < 8; ++i) {
            float w_ = __expf(a[i] - mx);
            l += w_;
            acc += w_ * V[i];
        }
        float o = q + acc / l;
        Opre1[(size_t)m * 64 + oc] = f2bf(o);
    }
}

// ===================== host launch =====================
extern "C" void kernel_launch(void* const* d_in, const int* in_sizes, int n_in,
                              void* d_out, int out_size, void* d_ws, size_t ws_size,
                              hipStream_t stream) {
    const float* X    = (const float*)d_in[0];
    const int*   hei  = (const int*)d_in[1];
    const float* I    = (const float*)d_in[2];
    const float* m0_wq = (const float*)d_in[3];
    const float* m0_bq = (const float*)d_in[4];
    const float* m0_wk = (const float*)d_in[5];
    const float* m0_bk = (const float*)d_in[6];
    const float* m0_wv = (const float*)d_in[7];
    const float* m0_bv = (const float*)d_in[8];
    const float* m0_wo = (const float*)d_in[9];
    const float* m0_bo = (const float*)d_in[10];
    const float* m1_wq = (const float*)d_in[11];
    const float* m1_bq = (const float*)d_in[12];
    const float* m1_wk = (const float*)d_in[13];
    const float* m1_bk = (const float*)d_in[14];
    const float* m1_wv = (const float*)d_in[15];
    const float* m1_bv = (const float*)d_in[16];
    const float* m1_wo = (const float*)d_in[17];
    const float* m1_bo = (const float*)d_in[18];

    const int* node = hei;           // [M]
    const int* edge = hei + MINC;    // [M]
    float* out = (float*)d_out;

    // -------- workspace layout (byte offsets) --------
    char* B = (char*)d_ws;
    short* Opre0 = (short*)B;                    // 20.48 MB (dead after fused_hkv)
    short* Opre1 = (short*)B;                    // 25.6 MB (aliases Opre0)
    short* K1    = (short*)(B + 26000000);       // 20.48 MB
    short* V1    = (short*)(B + 47000000);       // 20.48 MB
    short* Q1    = (short*)(B + 68000000);       // 6.4 MB
    short* V0    = (short*)(B + 75000000);       // 6.4 MB
    float* S0    = (float*)(B + 82000000);       // 6.4 MB
    float* QI    = (float*)(B + 89000000);       // 512 f
    float* Wf    = QI + 512;                     // 2048 f
    float* bfS   = Wf + 2048;                    // 32 f
    float* bias96 = bfS + 32;                    // 96 f
    short* PK    = (short*)(bias96 + 96);        // 29952 shorts
    short* WtO   = PK + 0;
    short* WtK   = PK + 4608;
    short* WtV   = PK + 9216;
    short* WtQ   = PK + 13824;
    short* WtF   = PK + 18432;
    short* Wt0   = PK + 23040;                   // 96x72
    int*   ib       = (int*)(PK + 29952);
    int*   rowstart = ib;                        // NE+1
    int*   cnt      = rowstart + (NEDGE + 1);    // NE
    int*   cursor   = cnt + NEDGE;               // NE
    int*   csr_node = cursor + NEDGE;            // M
    int*   csr_m    = csr_node + MINC;           // M

    // ---------------- setup ----------------
    qi_kernel<<<1, 512, 0, stream>>>(I, m0_wq, m0_bq, QI);
    fuse_kernel<<<1, 512, 0, stream>>>(QI, m0_wk, m0_bk, Wf, bfS);
    pack_kernel<<<5, 256, 0, stream>>>(m0_wo, m1_wk, m1_wv, m1_wq, m1_wo, PK);
    pack_dual_kernel<<<1, 256, 0, stream>>>(m0_wv, m0_bv, Wf, bfS, Wt0, bias96);

    hipMemsetAsync(cnt, 0, NEDGE * sizeof(int), stream);
    hist_kernel<<<(MINC + 255) / 256, 256, 0, stream>>>(edge, cnt);
    scan_kernel<<<1, 1024, 0, stream>>>(cnt, rowstart, cursor);
    scatter_kernel<<<(MINC + 255) / 256, 256, 0, stream>>>(node, edge, cursor,
                                                           csr_node, csr_m);

    // ---------------- Phase A: mab0 ----------------
    mfma_gemm_kernel<96, 0><<<(NNODES + 63) / 64, 256, 0, stream>>>(
        X, NNODES, Wt0, bias96, V0, S0);
    attn0_kernel<<<NEDGE / 4, 256, 0, stream>>>(V0, S0, QI, rowstart, csr_node, Opre0);

    // ---------------- Phase B: mab1 ----------------
    fused_hkv_mfma_kernel<<<NEDGE * NIND / 64, 256, 0, stream>>>(
        Opre0, WtO, m0_bo, WtK, m1_bk, WtV, m1_bv, K1, V1);
    mfma_gemm_kernel<64, 2><<<(NNODES + 63) / 64, 256, 0, stream>>>(
        X, NNODES, WtQ, m1_bq, Q1, nullptr);
    attn1_kernel<<<NEDGE / 4, 256, 0, stream>>>(
        Q1, K1, V1, rowstart, csr_node, csr_m, Opre1);
    mfma_gemm_kernel<64, 1><<<(MINC + 63) / 64, 256, 0, stream>>>(
        Opre1, MINC, WtF, m1_bo, out, nullptr);
}

// Round 5
// 221.025 us; speedup vs baseline: 2.5618x; 1.1197x over previous
//
#include <hip/hip_runtime.h>
#include <math.h>

#define NNODES 50000
#define MINC   200000
#define NEDGE  20000
#define NIND   8

typedef __attribute__((ext_vector_type(8))) short bf16x8;
typedef __attribute__((ext_vector_type(4))) float f32x4;

__device__ __forceinline__ short f2bf(float f) {
    union { float f; unsigned u; } x; x.f = f;
    unsigned r = x.u + 0x7FFF + ((x.u >> 16) & 1);
    return (short)(r >> 16);
}
__device__ __forceinline__ float bf2f(short s) {
    union { unsigned u; float f; } x; x.u = ((unsigned)(unsigned short)s) << 16;
    return x.f;
}
// perm maps: q(c)= (c&15)*4 + (c>>4)   [unperm col -> perm col]
//            sig(c)=(c&3)*16 + (c>>2)  [perm col  -> unperm col]
__device__ __forceinline__ int qperm(int c) { return ((c & 15) << 2) | (c >> 4); }
__device__ __forceinline__ int sigperm(int c) { return ((c & 3) << 4) | (c >> 2); }

// ============== setup: QI, Wf/bfS, bias160, all weight packing ==============
// one block, 512 threads
__global__ void setup_kernel(const float* __restrict__ I,
                             const float* __restrict__ m0_wq, const float* __restrict__ m0_bq,
                             const float* __restrict__ m0_wk, const float* __restrict__ m0_bk,
                             const float* __restrict__ m0_wv, const float* __restrict__ m0_bv,
                             const float* __restrict__ m1_wq, const float* __restrict__ m1_bq,
                             const float* __restrict__ m0_wo, const float* __restrict__ m1_wk,
                             const float* __restrict__ m1_wv, const float* __restrict__ m1_wo,
                             float* __restrict__ QI, float* __restrict__ bias160,
                             short* __restrict__ Wt0, short* __restrict__ WtO,
                             short* __restrict__ WtK, short* __restrict__ WtV,
                             short* __restrict__ WtF) {
    __shared__ float QIs[512];
    __shared__ float Wf[2048];
    __shared__ float bfS[32];
    int tid = threadIdx.x;
    // 1. QI = I @ m0_wq + m0_bq
    {
        int i = tid >> 6, c = tid & 63;
        float acc = m0_bq[c];
        for (int k = 0; k < 64; ++k) acc += I[i * 64 + k] * m0_wq[k * 64 + c];
        QIs[tid] = acc;
        QI[tid] = acc;
    }
    __syncthreads();
    // 2. Wf[k, i*4+h] = 0.125 * sum_d m0_wk[k, h*16+d] * QI[i, h*16+d]; bfS likewise
    for (int idx = tid; idx < 2048; idx += 512) {
        int k = idx >> 5, j = idx & 31;
        int i = j >> 2, h = j & 3;
        float s = 0.f;
        for (int d = 0; d < 16; ++d)
            s += m0_wk[k * 64 + h * 16 + d] * QIs[i * 64 + h * 16 + d];
        Wf[idx] = s * 0.125f;
    }
    if (tid < 32) {
        int i = tid >> 2, h = tid & 3;
        float s = 0.f;
        for (int d = 0; d < 16; ++d)
            s += m0_bk[h * 16 + d] * QIs[i * 64 + h * 16 + d];
        bfS[tid] = s * 0.125f;
    }
    __syncthreads();
    // 3. bias160 = [m0_bv | bfS | m1_bq]
    if (tid < 160)
        bias160[tid] = (tid < 64) ? m0_bv[tid] : ((tid < 96) ? bfS[tid - 64] : m1_bq[tid - 96]);
    // 4. Wt0[c][72]: rows 0-63 = m0_wv col, 64-95 = Wf col, 96-159 = m1_wq col (no perm)
    for (int idx = tid; idx < 160 * 72; idx += 512) {
        int c = idx / 72, k = idx % 72;
        short v = 0;
        if (k < 64) {
            float f = (c < 64) ? m0_wv[k * 64 + c]
                    : (c < 96) ? Wf[k * 32 + (c - 64)]
                               : m1_wq[k * 64 + (c - 96)];
            v = f2bf(f);
        }
        Wt0[idx] = v;
    }
    // 5. WtO (row+col perm), WtK/WtV/WtF (row perm)
    for (int mat = 0; mat < 4; ++mat) {
        const float* W = (mat == 0) ? m0_wo : (mat == 1) ? m1_wk : (mat == 2) ? m1_wv : m1_wo;
        short* D = (mat == 0) ? WtO : (mat == 1) ? WtK : (mat == 2) ? WtV : WtF;
        bool cperm = (mat == 0);
        for (int idx = tid; idx < 64 * 72; idx += 512) {
            int c = idx / 72, k = idx % 72;
            short v = 0;
            if (k < 64) {
                int kk = qperm(k);
                int cc = cperm ? qperm(c) : c;
                v = f2bf(W[kk * 64 + cc]);
            }
            D[idx] = v;
        }
    }
}

// ====== X GEMM: V0 = X@wv+bv (bf16), S0 = X@Wf+bfS (f32), Q1 = X@wq+bq (bf16) ======
__global__ void gemm_x_kernel(const float* __restrict__ A,
                              const short* __restrict__ Wt, const float* __restrict__ bias,
                              short* __restrict__ V0, float* __restrict__ S0,
                              short* __restrict__ Q1) {
    __shared__ short As[64 * 72];
    __shared__ short Ws[160 * 72];
    int tid = threadIdx.x;     // 256
    int row0 = blockIdx.x * 64;
    {
        const uint4* wsrc = (const uint4*)Wt;
        uint4* wdst = (uint4*)Ws;
        for (int k = tid; k < 160 * 9; k += 256) wdst[k] = wsrc[k];
    }
    {
        int r = tid >> 2, c0 = (tid & 3) * 16;
        int gr = row0 + r;
        float f[16];
        if (gr < NNODES) {
            const float4* src = (const float4*)(A + (size_t)gr * 64 + c0);
            #pragma unroll
            for (int j = 0; j < 4; ++j) {
                float4 t4 = src[j];
                f[4*j] = t4.x; f[4*j+1] = t4.y; f[4*j+2] = t4.z; f[4*j+3] = t4.w;
            }
        } else {
            #pragma unroll
            for (int j = 0; j < 16; ++j) f[j] = 0.f;
        }
        short tmp[16];
        #pragma unroll
        for (int j = 0; j < 16; ++j) tmp[j] = f2bf(f[j]);
        uint4* dst = (uint4*)&As[r * 72 + c0];
        dst[0] = *(const uint4*)&tmp[0];
        dst[1] = *(const uint4*)&tmp[8];
    }
    __syncthreads();
    int w = tid >> 6, l = tid & 63;
    int lr16 = l & 15, lk = (l >> 4) * 8;
    f32x4 acc[10] = {};
    #pragma unroll
    for (int ks = 0; ks < 2; ++ks) {
        bf16x8 a = *(const bf16x8*)&As[(w * 16 + lr16) * 72 + ks * 32 + lk];
        #pragma unroll
        for (int t = 0; t < 10; ++t) {
            bf16x8 b = *(const bf16x8*)&Ws[(t * 16 + lr16) * 72 + ks * 32 + lk];
            acc[t] = __builtin_amdgcn_mfma_f32_16x16x32_bf16(a, b, acc[t], 0, 0, 0);
        }
    }
    int rbase = w * 16 + (l >> 4) * 4;
    #pragma unroll
    for (int t = 0; t < 10; ++t) {
        int c = t * 16 + lr16;
        float bb = bias[c];
        #pragma unroll
        for (int r = 0; r < 4; ++r) {
            int gr = row0 + rbase + r;
            if (gr < NNODES) {
                float val = acc[t][r] + bb;
                if (c < 64) V0[(size_t)gr * 64 + c] = f2bf(val);
                else if (c < 96) S0[(size_t)gr * 32 + (c - 64)] = val;
                else Q1[(size_t)gr * 64 + (c - 96)] = f2bf(val);
            }
        }
    }
}

// === fused: H = Opre0 + relu(Opre0@wo'+bo') (LDS); K1 = 0.125*(H@wk'+bk); V1 = H@wv'+bv ===
__global__ void fused_hkv_mfma_kernel(const short* __restrict__ Opre0,
                                      const short* __restrict__ WtO, const float* __restrict__ bo,
                                      const short* __restrict__ WtK, const float* __restrict__ bk,
                                      const short* __restrict__ WtV, const float* __restrict__ bv,
                                      short* __restrict__ K1, short* __restrict__ V1) {
    __shared__ short As[64 * 72];
    __shared__ short Hs[64 * 72];
    __shared__ short Wo[64 * 72];
    __shared__ short Wk[64 * 72];
    __shared__ short Wv[64 * 72];
    int tid = threadIdx.x;   // 256
    int row0 = blockIdx.x * 64;   // 160000 % 64 == 0
    {
        uint4* d0 = (uint4*)Wo; const uint4* s0 = (const uint4*)WtO;
        uint4* d1 = (uint4*)Wk; const uint4* s1 = (const uint4*)WtK;
        uint4* d2 = (uint4*)Wv; const uint4* s2 = (const uint4*)WtV;
        for (int k = tid; k < 576; k += 256) { d0[k] = s0[k]; d1[k] = s1[k]; d2[k] = s2[k]; }
    }
    {
        int r = tid >> 2, c0 = (tid & 3) * 16;
        const uint4* src = (const uint4*)(Opre0 + (size_t)(row0 + r) * 64 + c0);
        uint4* dst = (uint4*)&As[r * 72 + c0];
        dst[0] = src[0]; dst[1] = src[1];
    }
    __syncthreads();
    int w = tid >> 6, l = tid & 63;
    int lr16 = l & 15, lk = (l >> 4) * 8;
    int rbase = w * 16 + (l >> 4) * 4;
    {
        f32x4 acc[4] = {};
        #pragma unroll
        for (int ks = 0; ks < 2; ++ks) {
            bf16x8 a = *(const bf16x8*)&As[(w * 16 + lr16) * 72 + ks * 32 + lk];
            #pragma unroll
            for (int t = 0; t < 4; ++t) {
                bf16x8 b = *(const bf16x8*)&Wo[(t * 16 + lr16) * 72 + ks * 32 + lk];
                acc[t] = __builtin_amdgcn_mfma_f32_16x16x32_bf16(a, b, acc[t], 0, 0, 0);
            }
        }
        #pragma unroll
        for (int t = 0; t < 4; ++t) {
            int c = t * 16 + lr16;
            float bb = bo[qperm(c)];          // col-permuted bias
            #pragma unroll
            for (int r = 0; r < 4; ++r) {
                float res = bf2f(As[(rbase + r) * 72 + c]);
                float hv = res + fmaxf(acc[t][r] + bb, 0.f);
                Hs[(rbase + r) * 72 + c] = f2bf(hv);
            }
        }
    }
    __syncthreads();
    {
        f32x4 ak[4] = {}, av[4] = {};
        #pragma unroll
        for (int ks = 0; ks < 2; ++ks) {
            bf16x8 a = *(const bf16x8*)&Hs[(w * 16 + lr16) * 72 + ks * 32 + lk];
            #pragma unroll
            for (int t = 0; t < 4; ++t) {
                bf16x8 b1 = *(const bf16x8*)&Wk[(t * 16 + lr16) * 72 + ks * 32 + lk];
                ak[t] = __builtin_amdgcn_mfma_f32_16x16x32_bf16(a, b1, ak[t], 0, 0, 0);
                bf16x8 b2 = *(const bf16x8*)&Wv[(t * 16 + lr16) * 72 + ks * 32 + lk];
                av[t] = __builtin_amdgcn_mfma_f32_16x16x32_bf16(a, b2, av[t], 0, 0, 0);
            }
        }
        #pragma unroll
        for (int t = 0; t < 4; ++t) {
            int c = t * 16 + lr16;
            float bbk = bk[c], bbv = bv[c];
            #pragma unroll
            for (int r = 0; r < 4; ++r) {
                size_t gr = (size_t)(row0 + rbase + r);
                K1[gr * 64 + c] = f2bf((ak[t][r] + bbk) * 0.125f);   // pre-scaled
                V1[gr * 64 + c] = f2bf(av[t][r] + bbv);
            }
        }
    }
}

// ===================== CSR build =====================
__global__ void hist_kernel(const int* __restrict__ edge, int* __restrict__ cnt) {
    int m = blockIdx.x * 256 + threadIdx.x;
    if (m < MINC) atomicAdd(&cnt[edge[m]], 1);
}

__global__ void scan_kernel(const int* __restrict__ cnt, int* __restrict__ rowstart,
                            int* __restrict__ cursor) {
    __shared__ int partial[1024];
    int tid = threadIdx.x;                       // 1024
    const int CH = (NEDGE + 1023) / 1024;        // 20
    int s = 0;
    for (int k = 0; k < CH; ++k) {
        int idx = tid * CH + k;
        if (idx < NEDGE) s += cnt[idx];
    }
    partial[tid] = s;
    __syncthreads();
    for (int off = 1; off < 1024; off <<= 1) {
        int v = 0;
        if (tid >= off) v = partial[tid - off];
        __syncthreads();
        if (tid >= off) partial[tid] += v;
        __syncthreads();
    }
    int base = (tid > 0) ? partial[tid - 1] : 0;
    for (int k = 0; k < CH; ++k) {
        int idx = tid * CH + k;
        if (idx < NEDGE) {
            rowstart[idx] = base;
            cursor[idx] = base;
            base += cnt[idx];
        }
    }
    if (tid == 1023) rowstart[NEDGE] = base;
}

__global__ void scatter_kernel(const int* __restrict__ node, const int* __restrict__ edge,
                               int* __restrict__ cursor, int* __restrict__ csr_node,
                               int* __restrict__ csr_m) {
    int m = blockIdx.x * 256 + threadIdx.x;
    if (m < MINC) {
        int e = edge[m];
        int pos = atomicAdd(&cursor[e], 1);
        csr_node[pos] = node[m];
        csr_m[pos] = m;
    }
}

// ============ mab0 attention: ONE WAVE PER EDGE, two-phase (unperm store) ============
#define CH0 32
__global__ void attn0_kernel(const short* __restrict__ V0, const float* __restrict__ S0,
                             const float* __restrict__ QI,
                             const int* __restrict__ rowstart, const int* __restrict__ csr_node,
                             short* __restrict__ Opre0) {
    __shared__ float Sw[4][CH0][32];
    __shared__ float Sc[4][32];
    __shared__ float Li[4][32];
    int w = threadIdx.x >> 6;
    int lane = threadIdx.x & 63;
    int e = blockIdx.x * 4 + w;
    int start = rowstart[e], end = rowstart[e + 1];
    int j = lane & 31;                       // i*4+h
    int pslot = lane >> 5;
    int tj = ((j & 3) << 3) | (j >> 2);      // h*8+i
    int h2 = lane >> 4;
    float runm = -INFINITY, lrun = 0.f;
    float acc[8] = {};
    for (int c0 = start; c0 < end; c0 += CH0) {
        int cnt = min(CH0, end - c0);
        float cm = -INFINITY;
        for (int p = pslot; p < cnt; p += 2) {
            int n = csr_node[c0 + p];
            float s = S0[(size_t)n * 32 + j];
            Sw[w][p][tj] = s;
            cm = fmaxf(cm, s);
        }
        cm = fmaxf(cm, __shfl_xor(cm, 32));
        float newm = fmaxf(runm, cm);
        float sc = __expf(runm - newm);
        runm = newm;
        float lsum = 0.f;
        for (int p = pslot; p < cnt; p += 2) {
            float s = Sw[w][p][tj];
            float w_ = __expf(s - newm);
            Sw[w][p][tj] = w_;
            lsum += w_;
        }
        lsum += __shfl_xor(lsum, 32);
        lrun = lrun * sc + lsum;
        if (pslot == 0) Sc[w][tj] = sc;
        asm volatile("s_waitcnt lgkmcnt(0)" ::: "memory");
        __builtin_amdgcn_sched_barrier(0);
        float4 sA = *(const float4*)&Sc[w][h2 * 8];
        float4 sB = *(const float4*)&Sc[w][h2 * 8 + 4];
        acc[0] *= sA.x; acc[1] *= sA.y; acc[2] *= sA.z; acc[3] *= sA.w;
        acc[4] *= sB.x; acc[5] *= sB.y; acc[6] *= sB.z; acc[7] *= sB.w;
        for (int p = 0; p < cnt; ++p) {
            int n = csr_node[c0 + p];
            float v = bf2f(V0[(size_t)n * 64 + lane]);
            float4 wA = *(const float4*)&Sw[w][p][h2 * 8];
            float4 wB = *(const float4*)&Sw[w][p][h2 * 8 + 4];
            acc[0] += wA.x * v; acc[1] += wA.y * v; acc[2] += wA.z * v; acc[3] += wA.w * v;
            acc[4] += wB.x * v; acc[5] += wB.y * v; acc[6] += wB.z * v; acc[7] += wB.w * v;
        }
    }
    if (pslot == 0) Li[w][tj] = lrun;
    asm volatile("s_waitcnt lgkmcnt(0)" ::: "memory");
    __builtin_amdgcn_sched_barrier(0);
    float4 lA = *(const float4*)&Li[w][h2 * 8];
    float4 lB = *(const float4*)&Li[w][h2 * 8 + 4];
    float li[8] = {lA.x, lA.y, lA.z, lA.w, lB.x, lB.y, lB.z, lB.w};
    #pragma unroll
    for (int i = 0; i < 8; ++i) {
        float qi = QI[i * 64 + lane];
        float o = qi + ((li[i] > 0.f) ? acc[i] / li[i] : 0.f);
        Opre0[(size_t)(e * NIND + i) * 64 + lane] = f2bf(o);   // UNPERMUTED store
    }
}

// ========== mab1 attention: packed dims, 2 incidences per wave pass ==========
__global__ void attn1_kernel(const short* __restrict__ Q1, const short* __restrict__ K1,
                             const short* __restrict__ V1,
                             const int* __restrict__ rowstart, const int* __restrict__ csr_node,
                             const int* __restrict__ csr_m,
                             short* __restrict__ Opre1) {
    int w = threadIdx.x >> 6;
    int lane = threadIdx.x & 63;
    int e = blockIdx.x * 4 + w;
    int sl = lane & 31;          // packed col: dims 2sl, 2sl+1 (head = sl>>3)
    int hw = lane >> 5;          // incidence slot 0/1
    float Klo[8], Khi[8], Vlo[8], Vhi[8];
    #pragma unroll
    for (int i = 0; i < 8; ++i) {
        unsigned kp = *(const unsigned*)&K1[(size_t)(e * 8 + i) * 64 + sl * 2];
        unsigned vp = *(const unsigned*)&V1[(size_t)(e * 8 + i) * 64 + sl * 2];
        Klo[i] = __int_as_float(kp << 16);
        Khi[i] = __int_as_float(kp & 0xffff0000u);
        Vlo[i] = __int_as_float(vp << 16);
        Vhi[i] = __int_as_float(vp & 0xffff0000u);
    }
    int start = rowstart[e], end = rowstart[e + 1];
    for (int p0 = start; p0 < end; p0 += 2) {
        int p = p0 + hw;
        bool valid = (p < end);
        int pc = valid ? p : (end - 1);
        int n = csr_node[pc];
        int m = csr_m[pc];
        unsigned qp = *(const unsigned*)&Q1[(size_t)n * 64 + sl * 2];
        float qlo = __int_as_float(qp << 16);
        float qhi = __int_as_float(qp & 0xffff0000u);
        float a[8];
        #pragma unroll
        for (int i = 0; i < 8; ++i) {
            float t = qlo * Klo[i] + qhi * Khi[i];   // K pre-scaled by 0.125
            t += __shfl_xor(t, 1);
            t += __shfl_xor(t, 2);
            t += __shfl_xor(t, 4);
            a[i] = t;
        }
        float mx = fmaxf(fmaxf(fmaxf(a[0], a[1]), fmaxf(a[2], a[3])),
                         fmaxf(fmaxf(a[4], a[5]), fmaxf(a[6], a[7])));
        float l = 0.f, acc0 = 0.f, acc1 = 0.f;
        #pragma unroll
        for (int i = 0; i < 8; ++i) {
            float w_ = __expf(a[i] - mx);
            l += w_;
            acc0 += w_ * Vlo[i];
            acc1 += w_ * Vhi[i];
        }
        float rl = 1.f / l;
        float o0 = qlo + acc0 * rl;
        float o1 = qhi + acc1 * rl;
        unsigned res = ((unsigned)(unsigned short)f2bf(o1) << 16)
                     | (unsigned)(unsigned short)f2bf(o0);
        if (valid) *(unsigned*)&Opre1[(size_t)m * 64 + sl * 2] = res;   // UNPERMUTED packed
    }
}

// ======= final GEMM: out = Opre1_perm + relu(Opre1_perm @ w + b), perm baked =======
__global__ void gemm_out_kernel(const short* __restrict__ Av,
                                const short* __restrict__ Wt, const float* __restrict__ bias,
                                float* __restrict__ out) {
    __shared__ short As[64 * 72];
    __shared__ short Ws[64 * 72];
    int tid = threadIdx.x;     // 256
    int row0 = blockIdx.x * 64;
    {
        const uint4* wsrc = (const uint4*)Wt;
        uint4* wdst = (uint4*)Ws;
        for (int k = tid; k < 576; k += 256) wdst[k] = wsrc[k];
    }
    {
        int r = tid >> 2, c0 = (tid & 3) * 16;
        int gr = row0 + r;
        uint4 a0 = {}, a1 = {};
        if (gr < MINC) {
            const uint4* src = (const uint4*)(Av + (size_t)gr * 64 + c0);
            a0 = src[0]; a1 = src[1];
        }
        uint4* dst = (uint4*)&As[r * 72 + c0];
        dst[0] = a0; dst[1] = a1;
    }
    __syncthreads();
    int w = tid >> 6, l = tid & 63;
    int lr16 = l & 15, lk = (l >> 4) * 8;
    f32x4 acc[4] = {};
    #pragma unroll
    for (int ks = 0; ks < 2; ++ks) {
        bf16x8 a = *(const bf16x8*)&As[(w * 16 + lr16) * 72 + ks * 32 + lk];
        #pragma unroll
        for (int t = 0; t < 4; ++t) {
            bf16x8 b = *(const bf16x8*)&Ws[(t * 16 + lr16) * 72 + ks * 32 + lk];
            acc[t] = __builtin_amdgcn_mfma_f32_16x16x32_bf16(a, b, acc[t], 0, 0, 0);
        }
    }
    int rbase = w * 16 + (l >> 4) * 4;
    #pragma unroll
    for (int t = 0; t < 4; ++t) {
        int c = t * 16 + lr16;           // output col (perm space)
        float bb = bias[c];
        int sc = sigperm(c);             // residual col in unperm LDS
        #pragma unroll
        for (int r = 0; r < 4; ++r) {
            int gr = row0 + rbase + r;
            if (gr < MINC) {
                float val = acc[t][r] + bb;
                float res = bf2f(As[(rbase + r) * 72 + sc]);
                out[(size_t)gr * 64 + c] = res + fmaxf(val, 0.f);
            }
        }
    }
}

// ===================== host launch =====================
extern "C" void kernel_launch(void* const* d_in, const int* in_sizes, int n_in,
                              void* d_out, int out_size, void* d_ws, size_t ws_size,
                              hipStream_t stream) {
    const float* X    = (const float*)d_in[0];
    const int*   hei  = (const int*)d_in[1];
    const float* I    = (const float*)d_in[2];
    const float* m0_wq = (const float*)d_in[3];
    const float* m0_bq = (const float*)d_in[4];
    const float* m0_wk = (const float*)d_in[5];
    const float* m0_bk = (const float*)d_in[6];
    const float* m0_wv = (const float*)d_in[7];
    const float* m0_bv = (const float*)d_in[8];
    const float* m0_wo = (const float*)d_in[9];
    const float* m0_bo = (const float*)d_in[10];
    const float* m1_wq = (const float*)d_in[11];
    const float* m1_bq = (const float*)d_in[12];
    const float* m1_wk = (const float*)d_in[13];
    const float* m1_bk = (const float*)d_in[14];
    const float* m1_wv = (const float*)d_in[15];
    const float* m1_bv = (const float*)d_in[16];
    const float* m1_wo = (const float*)d_in[17];
    const float* m1_bo = (const float*)d_in[18];

    const int* node = hei;           // [M]
    const int* edge = hei + MINC;    // [M]
    float* out = (float*)d_out;

    // -------- workspace layout (byte offsets) --------
    char* B = (char*)d_ws;
    short* Opre0 = (short*)B;                    // 20.48 MB (dead after fused_hkv)
    short* Opre1 = (short*)B;                    // 25.6 MB (aliases Opre0+V0, both dead)
    short* V0    = (short*)(B + 20480000);       // 6.4 MB
    float* S0    = (float*)(B + 26880000);       // 6.4 MB
    short* K1    = (short*)(B + 33280000);       // 20.48 MB
    short* V1    = (short*)(B + 53760000);       // 20.48 MB
    short* Q1    = (short*)(B + 74240000);       // 6.4 MB
    float* QI    = (float*)(B + 80640000);       // 512 f
    float* bias160 = QI + 512;                   // 160 f
    short* PK    = (short*)(bias160 + 160);
    short* Wt0   = PK;                           // 160*72
    short* WtO   = PK + 11520;
    short* WtK   = WtO + 4608;
    short* WtV   = WtK + 4608;
    short* WtF   = WtV + 4608;
    int*   ib       = (int*)(WtF + 4608);
    int*   rowstart = ib;                        // NE+1
    int*   cnt      = rowstart + (NEDGE + 1);    // NE
    int*   cursor   = cnt + NEDGE;               // NE
    int*   csr_node = cursor + NEDGE;            // M
    int*   csr_m    = csr_node + MINC;           // M

    // ---------------- setup + CSR ----------------
    setup_kernel<<<1, 512, 0, stream>>>(I, m0_wq, m0_bq, m0_wk, m0_bk, m0_wv, m0_bv,
                                        m1_wq, m1_bq, m0_wo, m1_wk, m1_wv, m1_wo,
                                        QI, bias160, Wt0, WtO, WtK, WtV, WtF);
    hipMemsetAsync(cnt, 0, NEDGE * sizeof(int), stream);
    hist_kernel<<<(MINC + 255) / 256, 256, 0, stream>>>(edge, cnt);
    scan_kernel<<<1, 1024, 0, stream>>>(cnt, rowstart, cursor);
    scatter_kernel<<<(MINC + 255) / 256, 256, 0, stream>>>(node, edge, cursor,
                                                           csr_node, csr_m);

    // ---------------- Phase A: mab0 ----------------
    gemm_x_kernel<<<(NNODES + 63) / 64, 256, 0, stream>>>(X, Wt0, bias160, V0, S0, Q1);
    attn0_kernel<<<NEDGE / 4, 256, 0, stream>>>(V0, S0, QI, rowstart, csr_node, Opre0);

    // ---------------- Phase B: mab1 ----------------
    fused_hkv_mfma_kernel<<<NEDGE * NIND / 64, 256, 0, stream>>>(
        Opre0, WtO, m0_bo, WtK, m1_bk, WtV, m1_bv, K1, V1);
    attn1_kernel<<<NEDGE / 4, 256, 0, stream>>>(
        Q1, K1, V1, rowstart, csr_node, csr_m, Opre1);
    gemm_out_kernel<<<(MINC + 63) / 64, 256, 0, stream>>>(Opre1, WtF, m1_bo, out);
}

// Round 6
// 215.947 us; speedup vs baseline: 2.6221x; 1.0235x over previous
//
#include <hip/hip_runtime.h>
#include <math.h>

#define NNODES 50000
#define MINC   200000
#define NEDGE  20000
#define NIND   8

typedef __attribute__((ext_vector_type(8))) short bf16x8;
typedef __attribute__((ext_vector_type(4))) float f32x4;

__device__ __forceinline__ short f2bf(float f) {
    union { float f; unsigned u; } x; x.f = f;
    unsigned r = x.u + 0x7FFF + ((x.u >> 16) & 1);
    return (short)(r >> 16);
}
__device__ __forceinline__ float bf2f(short s) {
    union { unsigned u; float f; } x; x.u = ((unsigned)(unsigned short)s) << 16;
    return x.f;
}
__device__ __forceinline__ int qperm(int c) { return ((c & 15) << 2) | (c >> 4); }
__device__ __forceinline__ int sigperm(int c) { return ((c & 3) << 4) | (c >> 2); }

// ============== setup: QI, Wf/bfS, bias160, all weight packing ==============
__global__ void setup_kernel(const float* __restrict__ I,
                             const float* __restrict__ m0_wq, const float* __restrict__ m0_bq,
                             const float* __restrict__ m0_wk, const float* __restrict__ m0_bk,
                             const float* __restrict__ m0_wv, const float* __restrict__ m0_bv,
                             const float* __restrict__ m1_wq, const float* __restrict__ m1_bq,
                             const float* __restrict__ m0_wo, const float* __restrict__ m1_wk,
                             const float* __restrict__ m1_wv, const float* __restrict__ m1_wo,
                             float* __restrict__ QI, float* __restrict__ bias160,
                             short* __restrict__ Wt0, short* __restrict__ WtO,
                             short* __restrict__ WtK, short* __restrict__ WtV,
                             short* __restrict__ WtF) {
    __shared__ float QIs[512];
    __shared__ float Wf[2048];
    __shared__ float bfS[32];
    int tid = threadIdx.x;
    {
        int i = tid >> 6, c = tid & 63;
        float acc = m0_bq[c];
        for (int k = 0; k < 64; ++k) acc += I[i * 64 + k] * m0_wq[k * 64 + c];
        QIs[tid] = acc;
        QI[tid] = acc;
    }
    __syncthreads();
    for (int idx = tid; idx < 2048; idx += 512) {
        int k = idx >> 5, j = idx & 31;
        int i = j >> 2, h = j & 3;
        float s = 0.f;
        for (int d = 0; d < 16; ++d)
            s += m0_wk[k * 64 + h * 16 + d] * QIs[i * 64 + h * 16 + d];
        Wf[idx] = s * 0.125f;
    }
    if (tid < 32) {
        int i = tid >> 2, h = tid & 3;
        float s = 0.f;
        for (int d = 0; d < 16; ++d)
            s += m0_bk[h * 16 + d] * QIs[i * 64 + h * 16 + d];
        bfS[tid] = s * 0.125f;
    }
    __syncthreads();
    if (tid < 160)
        bias160[tid] = (tid < 64) ? m0_bv[tid] : ((tid < 96) ? bfS[tid - 64] : m1_bq[tid - 96]);
    for (int idx = tid; idx < 160 * 72; idx += 512) {
        int c = idx / 72, k = idx % 72;
        short v = 0;
        if (k < 64) {
            float f = (c < 64) ? m0_wv[k * 64 + c]
                    : (c < 96) ? Wf[k * 32 + (c - 64)]
                               : m1_wq[k * 64 + (c - 96)];
            v = f2bf(f);
        }
        Wt0[idx] = v;
    }
    for (int mat = 0; mat < 4; ++mat) {
        const float* W = (mat == 0) ? m0_wo : (mat == 1) ? m1_wk : (mat == 2) ? m1_wv : m1_wo;
        short* D = (mat == 0) ? WtO : (mat == 1) ? WtK : (mat == 2) ? WtV : WtF;
        bool cperm = (mat == 0);
        for (int idx = tid; idx < 64 * 72; idx += 512) {
            int c = idx / 72, k = idx % 72;
            short v = 0;
            if (k < 64) {
                int kk = qperm(k);
                int cc = cperm ? qperm(c) : c;
                v = f2bf(W[kk * 64 + cc]);
            }
            D[idx] = v;
        }
    }
}

// ====== X GEMM (128 rows/block): V0 bf16, S0 f32, Q1 bf16 ======
__global__ void gemm_x_kernel(const float* __restrict__ A,
                              const short* __restrict__ Wt, const float* __restrict__ bias,
                              short* __restrict__ V0, float* __restrict__ S0,
                              short* __restrict__ Q1) {
    __shared__ short As[128 * 72];
    __shared__ short Ws[160 * 72];
    int tid = threadIdx.x;     // 256
    int row0 = blockIdx.x * 128;
    {
        const uint4* wsrc = (const uint4*)Wt;
        uint4* wdst = (uint4*)Ws;
        for (int k = tid; k < 1440; k += 256) wdst[k] = wsrc[k];
    }
    #pragma unroll
    for (int it = 0; it < 2; ++it) {
        int slot = tid + it * 256;
        int r = slot >> 2, c0 = (slot & 3) * 16;
        int gr = row0 + r;
        float f[16];
        if (gr < NNODES) {
            const float4* src = (const float4*)(A + (size_t)gr * 64 + c0);
            #pragma unroll
            for (int j = 0; j < 4; ++j) {
                float4 t4 = src[j];
                f[4*j] = t4.x; f[4*j+1] = t4.y; f[4*j+2] = t4.z; f[4*j+3] = t4.w;
            }
        } else {
            #pragma unroll
            for (int j = 0; j < 16; ++j) f[j] = 0.f;
        }
        short tmp[16];
        #pragma unroll
        for (int j = 0; j < 16; ++j) tmp[j] = f2bf(f[j]);
        uint4* dst = (uint4*)&As[r * 72 + c0];
        dst[0] = *(const uint4*)&tmp[0];
        dst[1] = *(const uint4*)&tmp[8];
    }
    __syncthreads();
    int w = tid >> 6, l = tid & 63;
    int lr16 = l & 15, lk = (l >> 4) * 8;
    f32x4 acc[2][10] = {};
    #pragma unroll
    for (int ks = 0; ks < 2; ++ks) {
        bf16x8 a0 = *(const bf16x8*)&As[(w * 16 + lr16) * 72 + ks * 32 + lk];
        bf16x8 a1 = *(const bf16x8*)&As[(64 + w * 16 + lr16) * 72 + ks * 32 + lk];
        #pragma unroll
        for (int t = 0; t < 10; ++t) {
            bf16x8 b = *(const bf16x8*)&Ws[(t * 16 + lr16) * 72 + ks * 32 + lk];
            acc[0][t] = __builtin_amdgcn_mfma_f32_16x16x32_bf16(a0, b, acc[0][t], 0, 0, 0);
            acc[1][t] = __builtin_amdgcn_mfma_f32_16x16x32_bf16(a1, b, acc[1][t], 0, 0, 0);
        }
    }
    int rbase = w * 16 + (l >> 4) * 4;
    #pragma unroll
    for (int rt = 0; rt < 2; ++rt) {
        #pragma unroll
        for (int t = 0; t < 10; ++t) {
            int c = t * 16 + lr16;
            float bb = bias[c];
            #pragma unroll
            for (int r = 0; r < 4; ++r) {
                int gr = row0 + rt * 64 + rbase + r;
                if (gr < NNODES) {
                    float val = acc[rt][t][r] + bb;
                    if (c < 64) V0[(size_t)gr * 64 + c] = f2bf(val);
                    else if (c < 96) S0[(size_t)gr * 32 + (c - 64)] = val;
                    else Q1[(size_t)gr * 64 + (c - 96)] = f2bf(val);
                }
            }
        }
    }
}

// === fused (128 rows/block): H = A + relu(A@wo'+bo'); K1 = 0.125*(H@wk'+bk); V1 = H@wv'+bv ===
__global__ void fused_hkv_mfma_kernel(const short* __restrict__ Opre0,
                                      const short* __restrict__ WtO, const float* __restrict__ bo,
                                      const short* __restrict__ WtK, const float* __restrict__ bk,
                                      const short* __restrict__ WtV, const float* __restrict__ bv,
                                      short* __restrict__ K1, short* __restrict__ V1) {
    __shared__ short As[128 * 72];
    __shared__ short Hs[128 * 72];
    __shared__ short Wo[64 * 72];
    __shared__ short Wk[64 * 72];
    __shared__ short Wv[64 * 72];
    int tid = threadIdx.x;   // 256
    int row0 = blockIdx.x * 128;   // 160000 % 128 == 0
    {
        uint4* d0 = (uint4*)Wo; const uint4* s0 = (const uint4*)WtO;
        uint4* d1 = (uint4*)Wk; const uint4* s1 = (const uint4*)WtK;
        uint4* d2 = (uint4*)Wv; const uint4* s2 = (const uint4*)WtV;
        for (int k = tid; k < 576; k += 256) { d0[k] = s0[k]; d1[k] = s1[k]; d2[k] = s2[k]; }
    }
    #pragma unroll
    for (int it = 0; it < 2; ++it) {
        int slot = tid + it * 256;
        int r = slot >> 2, c0 = (slot & 3) * 16;
        const uint4* src = (const uint4*)(Opre0 + (size_t)(row0 + r) * 64 + c0);
        uint4* dst = (uint4*)&As[r * 72 + c0];
        dst[0] = src[0]; dst[1] = src[1];
    }
    __syncthreads();
    int w = tid >> 6, l = tid & 63;
    int lr16 = l & 15, lk = (l >> 4) * 8;
    int rbase = w * 16 + (l >> 4) * 4;
    {
        f32x4 acc[2][4] = {};
        #pragma unroll
        for (int ks = 0; ks < 2; ++ks) {
            bf16x8 a0 = *(const bf16x8*)&As[(w * 16 + lr16) * 72 + ks * 32 + lk];
            bf16x8 a1 = *(const bf16x8*)&As[(64 + w * 16 + lr16) * 72 + ks * 32 + lk];
            #pragma unroll
            for (int t = 0; t < 4; ++t) {
                bf16x8 b = *(const bf16x8*)&Wo[(t * 16 + lr16) * 72 + ks * 32 + lk];
                acc[0][t] = __builtin_amdgcn_mfma_f32_16x16x32_bf16(a0, b, acc[0][t], 0, 0, 0);
                acc[1][t] = __builtin_amdgcn_mfma_f32_16x16x32_bf16(a1, b, acc[1][t], 0, 0, 0);
            }
        }
        #pragma unroll
        for (int rt = 0; rt < 2; ++rt) {
            #pragma unroll
            for (int t = 0; t < 4; ++t) {
                int c = t * 16 + lr16;
                float bb = bo[qperm(c)];
                #pragma unroll
                for (int r = 0; r < 4; ++r) {
                    int rr = rt * 64 + rbase + r;
                    float res = bf2f(As[rr * 72 + c]);
                    float hv = res + fmaxf(acc[rt][t][r] + bb, 0.f);
                    Hs[rr * 72 + c] = f2bf(hv);
                }
            }
        }
    }
    __syncthreads();
    {
        f32x4 ak[2][4] = {}, av[2][4] = {};
        #pragma unroll
        for (int ks = 0; ks < 2; ++ks) {
            bf16x8 a0 = *(const bf16x8*)&Hs[(w * 16 + lr16) * 72 + ks * 32 + lk];
            bf16x8 a1 = *(const bf16x8*)&Hs[(64 + w * 16 + lr16) * 72 + ks * 32 + lk];
            #pragma unroll
            for (int t = 0; t < 4; ++t) {
                bf16x8 b1 = *(const bf16x8*)&Wk[(t * 16 + lr16) * 72 + ks * 32 + lk];
                ak[0][t] = __builtin_amdgcn_mfma_f32_16x16x32_bf16(a0, b1, ak[0][t], 0, 0, 0);
                ak[1][t] = __builtin_amdgcn_mfma_f32_16x16x32_bf16(a1, b1, ak[1][t], 0, 0, 0);
                bf16x8 b2 = *(const bf16x8*)&Wv[(t * 16 + lr16) * 72 + ks * 32 + lk];
                av[0][t] = __builtin_amdgcn_mfma_f32_16x16x32_bf16(a0, b2, av[0][t], 0, 0, 0);
                av[1][t] = __builtin_amdgcn_mfma_f32_16x16x32_bf16(a1, b2, av[1][t], 0, 0, 0);
            }
        }
        #pragma unroll
        for (int rt = 0; rt < 2; ++rt) {
            #pragma unroll
            for (int t = 0; t < 4; ++t) {
                int c = t * 16 + lr16;
                float bbk = bk[c], bbv = bv[c];
                #pragma unroll
                for (int r = 0; r < 4; ++r) {
                    size_t gr = (size_t)(row0 + rt * 64 + rbase + r);
                    K1[gr * 64 + c] = f2bf((ak[rt][t][r] + bbk) * 0.125f);
                    V1[gr * 64 + c] = f2bf(av[rt][t][r] + bbv);
                }
            }
        }
    }
}

// ===================== CSR build =====================
__global__ void hist_kernel(const int* __restrict__ edge, int* __restrict__ cnt) {
    int m = blockIdx.x * 256 + threadIdx.x;
    if (m < MINC) atomicAdd(&cnt[edge[m]], 1);
}

__global__ void scan_kernel(const int* __restrict__ cnt, int* __restrict__ rowstart,
                            int* __restrict__ cursor) {
    __shared__ int partial[1024];
    int tid = threadIdx.x;                       // 1024
    const int CH = (NEDGE + 1023) / 1024;        // 20
    int s = 0;
    for (int k = 0; k < CH; ++k) {
        int idx = tid * CH + k;
        if (idx < NEDGE) s += cnt[idx];
    }
    partial[tid] = s;
    __syncthreads();
    for (int off = 1; off < 1024; off <<= 1) {
        int v = 0;
        if (tid >= off) v = partial[tid - off];
        __syncthreads();
        if (tid >= off) partial[tid] += v;
        __syncthreads();
    }
    int base = (tid > 0) ? partial[tid - 1] : 0;
    for (int k = 0; k < CH; ++k) {
        int idx = tid * CH + k;
        if (idx < NEDGE) {
            rowstart[idx] = base;
            cursor[idx] = base;
            base += cnt[idx];
        }
    }
    if (tid == 1023) rowstart[NEDGE] = base;
}

__global__ void scatter_kernel(const int* __restrict__ node, const int* __restrict__ edge,
                               int* __restrict__ cursor, int* __restrict__ csr_node,
                               int* __restrict__ csr_m) {
    int m = blockIdx.x * 256 + threadIdx.x;
    if (m < MINC) {
        int e = edge[m];
        int pos = atomicAdd(&cursor[e], 1);
        csr_node[pos] = node[m];
        csr_m[pos] = m;
    }
}

// ============ mab0 attention: ONE WAVE PER EDGE, two-phase (unperm store) ============
#define CH0 32
__global__ void attn0_kernel(const short* __restrict__ V0, const float* __restrict__ S0,
                             const float* __restrict__ QI,
                             const int* __restrict__ rowstart, const int* __restrict__ csr_node,
                             short* __restrict__ Opre0) {
    __shared__ float Sw[4][CH0][32];
    __shared__ float Sc[4][32];
    __shared__ float Li[4][32];
    int w = threadIdx.x >> 6;
    int lane = threadIdx.x & 63;
    int e = blockIdx.x * 4 + w;
    int start = rowstart[e], end = rowstart[e + 1];
    int j = lane & 31;                       // i*4+h
    int pslot = lane >> 5;
    int tj = ((j & 3) << 3) | (j >> 2);      // h*8+i
    int h2 = lane >> 4;
    float runm = -INFINITY, lrun = 0.f;
    float acc[8] = {};
    for (int c0 = start; c0 < end; c0 += CH0) {
        int cnt = min(CH0, end - c0);
        float cm = -INFINITY;
        for (int p = pslot; p < cnt; p += 2) {
            int n = csr_node[c0 + p];
            float s = S0[(size_t)n * 32 + j];
            Sw[w][p][tj] = s;
            cm = fmaxf(cm, s);
        }
        cm = fmaxf(cm, __shfl_xor(cm, 32));
        float newm = fmaxf(runm, cm);
        float sc = __expf(runm - newm);
        runm = newm;
        float lsum = 0.f;
        for (int p = pslot; p < cnt; p += 2) {
            float s = Sw[w][p][tj];
            float w_ = __expf(s - newm);
            Sw[w][p][tj] = w_;
            lsum += w_;
        }
        lsum += __shfl_xor(lsum, 32);
        lrun = lrun * sc + lsum;
        if (pslot == 0) Sc[w][tj] = sc;
        asm volatile("s_waitcnt lgkmcnt(0)" ::: "memory");
        __builtin_amdgcn_sched_barrier(0);
        float4 sA = *(const float4*)&Sc[w][h2 * 8];
        float4 sB = *(const float4*)&Sc[w][h2 * 8 + 4];
        acc[0] *= sA.x; acc[1] *= sA.y; acc[2] *= sA.z; acc[3] *= sA.w;
        acc[4] *= sB.x; acc[5] *= sB.y; acc[6] *= sB.z; acc[7] *= sB.w;
        for (int p = 0; p < cnt; ++p) {
            int n = csr_node[c0 + p];
            float v = bf2f(V0[(size_t)n * 64 + lane]);
            float4 wA = *(const float4*)&Sw[w][p][h2 * 8];
            float4 wB = *(const float4*)&Sw[w][p][h2 * 8 + 4];
            acc[0] += wA.x * v; acc[1] += wA.y * v; acc[2] += wA.z * v; acc[3] += wA.w * v;
            acc[4] += wB.x * v; acc[5] += wB.y * v; acc[6] += wB.z * v; acc[7] += wB.w * v;
        }
    }
    if (pslot == 0) Li[w][tj] = lrun;
    asm volatile("s_waitcnt lgkmcnt(0)" ::: "memory");
    __builtin_amdgcn_sched_barrier(0);
    float4 lA = *(const float4*)&Li[w][h2 * 8];
    float4 lB = *(const float4*)&Li[w][h2 * 8 + 4];
    float li[8] = {lA.x, lA.y, lA.z, lA.w, lB.x, lB.y, lB.z, lB.w};
    #pragma unroll
    for (int i = 0; i < 8; ++i) {
        float qi = QI[i * 64 + lane];
        float o = qi + ((li[i] > 0.f) ? acc[i] / li[i] : 0.f);
        Opre0[(size_t)(e * NIND + i) * 64 + lane] = f2bf(o);
    }
}

// ========== mab1 attention: 4 dims/lane, 4 incidences per wave pass ==========
__global__ void attn1_kernel(const short* __restrict__ Q1, const short* __restrict__ K1,
                             const short* __restrict__ V1,
                             const int* __restrict__ rowstart, const int* __restrict__ csr_node,
                             const int* __restrict__ csr_m,
                             short* __restrict__ Opre1) {
    int w = threadIdx.x >> 6;
    int lane = threadIdx.x & 63;
    int e = blockIdx.x * 4 + w;
    int sl4 = lane & 15;          // dims 4*sl4 .. 4*sl4+3; head = sl4>>2 (quad-aligned)
    int inc = lane >> 4;          // incidence slot 0..3
    float Kf[8][4], Vf[8][4];
    #pragma unroll
    for (int i = 0; i < 8; ++i) {
        uint2 kp = *(const uint2*)&K1[(size_t)(e * 8 + i) * 64 + sl4 * 4];
        uint2 vp = *(const uint2*)&V1[(size_t)(e * 8 + i) * 64 + sl4 * 4];
        Kf[i][0] = __int_as_float(kp.x << 16);
        Kf[i][1] = __int_as_float(kp.x & 0xffff0000u);
        Kf[i][2] = __int_as_float(kp.y << 16);
        Kf[i][3] = __int_as_float(kp.y & 0xffff0000u);
        Vf[i][0] = __int_as_float(vp.x << 16);
        Vf[i][1] = __int_as_float(vp.x & 0xffff0000u);
        Vf[i][2] = __int_as_float(vp.y << 16);
        Vf[i][3] = __int_as_float(vp.y & 0xffff0000u);
    }
    int start = rowstart[e], end = rowstart[e + 1];
    for (int p0 = start; p0 < end; p0 += 4) {
        int p = p0 + inc;
        bool valid = (p < end);
        int pc = valid ? p : (end - 1);
        int n = csr_node[pc];
        int m = csr_m[pc];
        uint2 qp = *(const uint2*)&Q1[(size_t)n * 64 + sl4 * 4];
        float qa0 = __int_as_float(qp.x << 16);
        float qa1 = __int_as_float(qp.x & 0xffff0000u);
        float qa2 = __int_as_float(qp.y << 16);
        float qa3 = __int_as_float(qp.y & 0xffff0000u);
        float a[8];
        #pragma unroll
        for (int i = 0; i < 8; ++i) {
            float t = qa0 * Kf[i][0] + qa1 * Kf[i][1] + qa2 * Kf[i][2] + qa3 * Kf[i][3];
            int tv = __builtin_amdgcn_update_dpp(0, __float_as_int(t), 0xB1, 0xf, 0xf, true);
            t += __int_as_float(tv);                 // quad xor1
            tv = __builtin_amdgcn_update_dpp(0, __float_as_int(t), 0x4E, 0xf, 0xf, true);
            t += __int_as_float(tv);                 // quad xor2
            a[i] = t;                                 // K pre-scaled by 0.125
        }
        float mx = fmaxf(fmaxf(fmaxf(a[0], a[1]), fmaxf(a[2], a[3])),
                         fmaxf(fmaxf(a[4], a[5]), fmaxf(a[6], a[7])));
        float l = 0.f, ac0 = 0.f, ac1 = 0.f, ac2 = 0.f, ac3 = 0.f;
        #pragma unroll
        for (int i = 0; i < 8; ++i) {
            float w_ = __expf(a[i] - mx);
            l += w_;
            ac0 += w_ * Vf[i][0];
            ac1 += w_ * Vf[i][1];
            ac2 += w_ * Vf[i][2];
            ac3 += w_ * Vf[i][3];
        }
        float rl = 1.f / l;
        float o0 = qa0 + ac0 * rl;
        float o1 = qa1 + ac1 * rl;
        float o2 = qa2 + ac2 * rl;
        float o3 = qa3 + ac3 * rl;
        uint2 res;
        res.x = ((unsigned)(unsigned short)f2bf(o1) << 16) | (unsigned)(unsigned short)f2bf(o0);
        res.y = ((unsigned)(unsigned short)f2bf(o3) << 16) | (unsigned)(unsigned short)f2bf(o2);
        if (valid) *(uint2*)&Opre1[(size_t)m * 64 + sl4 * 4] = res;
    }
}

// ======= final GEMM (128 rows/block): out = res + relu(A@w+b), perm baked =======
__global__ void gemm_out_kernel(const short* __restrict__ Av,
                                const short* __restrict__ Wt, const float* __restrict__ bias,
                                float* __restrict__ out) {
    __shared__ short As[128 * 72];
    __shared__ short Ws[64 * 72];
    int tid = threadIdx.x;     // 256
    int row0 = blockIdx.x * 128;
    {
        const uint4* wsrc = (const uint4*)Wt;
        uint4* wdst = (uint4*)Ws;
        for (int k = tid; k < 576; k += 256) wdst[k] = wsrc[k];
    }
    #pragma unroll
    for (int it = 0; it < 2; ++it) {
        int slot = tid + it * 256;
        int r = slot >> 2, c0 = (slot & 3) * 16;
        int gr = row0 + r;
        uint4 a0 = {}, a1 = {};
        if (gr < MINC) {
            const uint4* src = (const uint4*)(Av + (size_t)gr * 64 + c0);
            a0 = src[0]; a1 = src[1];
        }
        uint4* dst = (uint4*)&As[r * 72 + c0];
        dst[0] = a0; dst[1] = a1;
    }
    __syncthreads();
    int w = tid >> 6, l = tid & 63;
    int lr16 = l & 15, lk = (l >> 4) * 8;
    f32x4 acc[2][4] = {};
    #pragma unroll
    for (int ks = 0; ks < 2; ++ks) {
        bf16x8 a0 = *(const bf16x8*)&As[(w * 16 + lr16) * 72 + ks * 32 + lk];
        bf16x8 a1 = *(const bf16x8*)&As[(64 + w * 16 + lr16) * 72 + ks * 32 + lk];
        #pragma unroll
        for (int t = 0; t < 4; ++t) {
            bf16x8 b = *(const bf16x8*)&Ws[(t * 16 + lr16) * 72 + ks * 32 + lk];
            acc[0][t] = __builtin_amdgcn_mfma_f32_16x16x32_bf16(a0, b, acc[0][t], 0, 0, 0);
            acc[1][t] = __builtin_amdgcn_mfma_f32_16x16x32_bf16(a1, b, acc[1][t], 0, 0, 0);
        }
    }
    int rbase = w * 16 + (l >> 4) * 4;
    #pragma unroll
    for (int rt = 0; rt < 2; ++rt) {
        #pragma unroll
        for (int t = 0; t < 4; ++t) {
            int c = t * 16 + lr16;
            float bb = bias[c];
            int sc = sigperm(c);
            #pragma unroll
            for (int r = 0; r < 4; ++r) {
                int gr = row0 + rt * 64 + rbase + r;
                if (gr < MINC) {
                    float val = acc[rt][t][r] + bb;
                    float res = bf2f(As[(rt * 64 + rbase + r) * 72 + sc]);
                    out[(size_t)gr * 64 + c] = res + fmaxf(val, 0.f);
                }
            }
        }
    }
}

// ===================== host launch =====================
extern "C" void kernel_launch(void* const* d_in, const int* in_sizes, int n_in,
                              void* d_out, int out_size, void* d_ws, size_t ws_size,
                              hipStream_t stream) {
    const float* X    = (const float*)d_in[0];
    const int*   hei  = (const int*)d_in[1];
    const float* I    = (const float*)d_in[2];
    const float* m0_wq = (const float*)d_in[3];
    const float* m0_bq = (const float*)d_in[4];
    const float* m0_wk = (const float*)d_in[5];
    const float* m0_bk = (const float*)d_in[6];
    const float* m0_wv = (const float*)d_in[7];
    const float* m0_bv = (const float*)d_in[8];
    const float* m0_wo = (const float*)d_in[9];
    const float* m0_bo = (const float*)d_in[10];
    const float* m1_wq = (const float*)d_in[11];
    const float* m1_bq = (const float*)d_in[12];
    const float* m1_wk = (const float*)d_in[13];
    const float* m1_bk = (const float*)d_in[14];
    const float* m1_wv = (const float*)d_in[15];
    const float* m1_bv = (const float*)d_in[16];
    const float* m1_wo = (const float*)d_in[17];
    const float* m1_bo = (const float*)d_in[18];

    const int* node = hei;           // [M]
    const int* edge = hei + MINC;    // [M]
    float* out = (float*)d_out;

    // -------- workspace layout (byte offsets) --------
    char* B = (char*)d_ws;
    short* Opre0 = (short*)B;                    // 20.48 MB (dead after fused_hkv)
    short* Opre1 = (short*)B;                    // 25.6 MB (aliases Opre0+V0, both dead)
    short* V0    = (short*)(B + 20480000);       // 6.4 MB
    float* S0    = (float*)(B + 26880000);       // 6.4 MB
    short* K1    = (short*)(B + 33280000);       // 20.48 MB
    short* V1    = (short*)(B + 53760000);       // 20.48 MB
    short* Q1    = (short*)(B + 74240000);       // 6.4 MB
    float* QI    = (float*)(B + 80640000);       // 512 f
    float* bias160 = QI + 512;                   // 160 f
    short* PK    = (short*)(bias160 + 160);
    short* Wt0   = PK;                           // 160*72
    short* WtO   = PK + 11520;
    short* WtK   = WtO + 4608;
    short* WtV   = WtK + 4608;
    short* WtF   = WtV + 4608;
    int*   ib       = (int*)(WtF + 4608);
    int*   rowstart = ib;                        // NE+1
    int*   cnt      = rowstart + (NEDGE + 1);    // NE
    int*   cursor   = cnt + NEDGE;               // NE
    int*   csr_node = cursor + NEDGE;            // M
    int*   csr_m    = csr_node + MINC;           // M

    // ---------------- setup + CSR ----------------
    setup_kernel<<<1, 512, 0, stream>>>(I, m0_wq, m0_bq, m0_wk, m0_bk, m0_wv, m0_bv,
                                        m1_wq, m1_bq, m0_wo, m1_wk, m1_wv, m1_wo,
                                        QI, bias160, Wt0, WtO, WtK, WtV, WtF);
    hipMemsetAsync(cnt, 0, NEDGE * sizeof(int), stream);
    hist_kernel<<<(MINC + 255) / 256, 256, 0, stream>>>(edge, cnt);
    scan_kernel<<<1, 1024, 0, stream>>>(cnt, rowstart, cursor);
    scatter_kernel<<<(MINC + 255) / 256, 256, 0, stream>>>(node, edge, cursor,
                                                           csr_node, csr_m);

    // ---------------- Phase A: mab0 ----------------
    gemm_x_kernel<<<(NNODES + 127) / 128, 256, 0, stream>>>(X, Wt0, bias160, V0, S0, Q1);
    attn0_kernel<<<NEDGE / 4, 256, 0, stream>>>(V0, S0, QI, rowstart, csr_node, Opre0);

    // ---------------- Phase B: mab1 ----------------
    fused_hkv_mfma_kernel<<<NEDGE * NIND / 128, 256, 0, stream>>>(
        Opre0, WtO, m0_bo, WtK, m1_bk, WtV, m1_bv, K1, V1);
    attn1_kernel<<<NEDGE / 4, 256, 0, stream>>>(
        Q1, K1, V1, rowstart, csr_node, csr_m, Opre1);
    gemm_out_kernel<<<(MINC + 127) / 128, 256, 0, stream>>>(Opre1, WtF, m1_bo, out);
}